// Round 6
// baseline (2162.403 us; speedup 1.0000x reference)
//
#include <hip/hip_runtime.h>
#include <hip/hip_bf16.h>

typedef __hip_bfloat16 bf16;

#define BB 8
#define NN 2048
#define CC 9
#define KK 20

// ---------------- ws layout (float elements) ----------------
static constexpr int OFF_X1   = 0;               // 1048576 (16384x64 fp32)
static constexpr int OFF_X2   = 1048576;         // 1048576
static constexpr int OFF_X3   = 2097152;         // 1048576 (fp32 now)
static constexpr int OFF_SQN  = 3145728;         // 16384
static constexpr int OFF_GMAX = 3162112;         // 8192
static constexpr int OFF_PART = 3170304;         // 262144 (256x1024)
static constexpr int OFF_STATS= 3432448;         // 12800 (4224 doubles + 4224 floats)
static constexpr int OFF_IDX  = 3445248;         // 327680 (int32)
static constexpr int BASE_END = 3772928;         // 15.1 MB
// tier A: H7 fp32 (16384x512) at BASE_END -> end 12,161,536 fl (48.6 MB)
// tier B: H8 fp32 (16384x256) at BASE_END -> end  7,967,232 fl (31.9 MB)
// tier C: H8 bf16 aliases X1+X2 (as R5)
//
// d_out scratch (out1 region, 4194304 fl): P|Q (2M) then GRAM (4.19M) then H7-bf16 (tiers B/C)

__device__ __forceinline__ float lrelu(float x){ return x >= 0.f ? x : 0.2f * x; }

__device__ __forceinline__ void store4(float* p, float a, float b, float c, float d){
    *(float4*)p = make_float4(a,b,c,d);
}
__device__ __forceinline__ void store4(bf16* p, float a, float b, float c, float d){
    union { bf16 h[4]; uint2 u; } pk;
    pk.h[0] = (bf16)a; pk.h[1] = (bf16)b; pk.h[2] = (bf16)c; pk.h[3] = (bf16)d;
    *(uint2*)p = pk.u;
}

// ---------------- K0: echo (B,C,N) -> (B,N,C) fp32 ----------------
__global__ void k_echo(const float* __restrict__ x, float* __restrict__ out0){
    int t = blockIdx.x * 256 + threadIdx.x;
    if (t >= BB*CC*NN) return;
    int b = t / (CC*NN); int r = t % (CC*NN); int c = r / NN; int n = r % NN;
    out0[(b*NN + n)*CC + c] = x[t];
}

// ---------------- K1: knn on 3-d coords (channels 6..8) ----------------
__global__ __launch_bounds__(256) void k_knn3(const float* __restrict__ x, int* __restrict__ idx){
    __shared__ float crd[NN*3];
    int b  = blockIdx.x / (NN/4);
    int rb = blockIdx.x % (NN/4);
    for (int c = 0; c < 3; c++)
        for (int p = threadIdx.x; p < NN; p += 256)
            crd[p*3 + c] = x[(b*CC + 6 + c)*NN + p];
    __syncthreads();
    int lane = threadIdx.x & 63;
    int n = rb*4 + (threadIdx.x >> 6);
    float qx = crd[n*3], qy = crd[n*3+1], qz = crd[n*3+2];
    float sqn = qx*qx + qy*qy + qz*qz;
    float d[32];
    #pragma unroll
    for (int j = 0; j < 32; j++){
        int m = j*64 + lane;
        float mx = crd[m*3], my = crd[m*3+1], mz = crd[m*3+2];
        d[j] = 2.f*(qx*mx + qy*my + qz*mz) - sqn - (mx*mx + my*my + mz*mz);
    }
    int* orow = idx + (b*NN + n)*KK;
    for (int it = 0; it < KK; it++){
        float bv = d[0]; int bm = lane;
        #pragma unroll
        for (int j = 1; j < 32; j++){
            if (d[j] > bv){ bv = d[j]; bm = j*64 + lane; }
        }
        #pragma unroll
        for (int off = 32; off >= 1; off >>= 1){
            float ov = __shfl_xor(bv, off);
            int   om = __shfl_xor(bm, off);
            if (ov > bv || (ov == bv && om < bm)){ bv = ov; bm = om; }
        }
        if (lane == 0) orow[it] = bm;
        if ((bm & 63) == lane) d[bm >> 6] = -INFINITY;
    }
}

// ---------------- P/Q stage 1 ----------------
__global__ __launch_bounds__(256) void k_pq9(const float* __restrict__ x, const float* __restrict__ w,
                                             float* __restrict__ P, float* __restrict__ Q){
    __shared__ __align__(16) float Xs[64*16];
    __shared__ __align__(16) float Wp[12*68];
    __shared__ __align__(16) float Wq[12*68];
    int row0 = blockIdx.x * 64;
    int b  = row0 >> 11;
    int n0 = row0 & (NN-1);
    int tx = threadIdx.x & 15, ty = threadIdx.x >> 4;
    for (int i = threadIdx.x; i < 64*12; i += 256){
        int r = i & 63, c = i >> 6;
        Xs[r*16 + c] = (c < 9) ? x[(b*CC + c)*NN + n0 + r] : 0.f;
    }
    for (int i = threadIdx.x; i < 64*12; i += 256){
        int c = i % 12, o = i / 12;
        float a = 0.f, dd = 0.f;
        if (c < 9){
            a  = w[o*18 + c];
            dd = w[o*18 + 9 + c] - a;
        }
        Wp[c*68 + o] = a;
        Wq[c*68 + o] = dd;
    }
    __syncthreads();
    float ap[4][4] = {{0.f}}, aq[4][4] = {{0.f}};
    for (int c0 = 0; c0 < 12; c0 += 4){
        float wp4[16], wq4[16];
        #pragma unroll
        for (int q = 0; q < 4; q++){
            *(float4*)&wp4[q*4] = *(const float4*)&Wp[(c0 + q)*68 + tx*4];
            *(float4*)&wq4[q*4] = *(const float4*)&Wq[(c0 + q)*68 + tx*4];
        }
        #pragma unroll
        for (int ii = 0; ii < 4; ii++){
            float4 x4 = *(const float4*)&Xs[(ty*4 + ii)*16 + c0];
            #pragma unroll
            for (int jj = 0; jj < 4; jj++){
                ap[ii][jj] += x4.x*wp4[jj] + x4.y*wp4[4+jj] + x4.z*wp4[8+jj] + x4.w*wp4[12+jj];
                aq[ii][jj] += x4.x*wq4[jj] + x4.y*wq4[4+jj] + x4.z*wq4[8+jj] + x4.w*wq4[12+jj];
            }
        }
    }
    #pragma unroll
    for (int ii = 0; ii < 4; ii++){
        int row = row0 + ty*4 + ii;
        store4(&P[row*64 + tx*4], ap[ii][0], ap[ii][1], ap[ii][2], ap[ii][3]);
        store4(&Q[row*64 + tx*4], aq[ii][0], aq[ii][1], aq[ii][2], aq[ii][3]);
    }
}

// ---------------- P/Q stages 2/3 ----------------
__global__ __launch_bounds__(256) void k_pq64(const float* __restrict__ X, const float* __restrict__ w,
                                              float* __restrict__ P, float* __restrict__ Q){
    __shared__ __align__(16) float Xs[64*68];
    __shared__ __align__(16) float Wp[64*68];
    __shared__ __align__(16) float Wq[64*68];
    int row0 = blockIdx.x * 64;
    int tx = threadIdx.x & 15, ty = threadIdx.x >> 4;
    for (int i = threadIdx.x; i < 64*64; i += 256){
        int c = i & 63, r = i >> 6;
        Xs[r*68 + c] = X[(row0 + r)*64 + c];
    }
    for (int i = threadIdx.x; i < 64*64; i += 256){
        int c = i & 63, o = i >> 6;
        float a  = w[o*128 + c];
        Wp[c*68 + o] = a;
        Wq[c*68 + o] = w[o*128 + 64 + c] - a;
    }
    __syncthreads();
    float ap[4][4] = {{0.f}}, aq[4][4] = {{0.f}};
    for (int c0 = 0; c0 < 64; c0 += 4){
        float wp4[16], wq4[16];
        #pragma unroll
        for (int q = 0; q < 4; q++){
            *(float4*)&wp4[q*4] = *(const float4*)&Wp[(c0 + q)*68 + tx*4];
            *(float4*)&wq4[q*4] = *(const float4*)&Wq[(c0 + q)*68 + tx*4];
        }
        #pragma unroll
        for (int ii = 0; ii < 4; ii++){
            float4 x4 = *(const float4*)&Xs[(ty*4 + ii)*68 + c0];
            #pragma unroll
            for (int jj = 0; jj < 4; jj++){
                ap[ii][jj] += x4.x*wp4[jj] + x4.y*wp4[4+jj] + x4.z*wp4[8+jj] + x4.w*wp4[12+jj];
                aq[ii][jj] += x4.x*wq4[jj] + x4.y*wq4[4+jj] + x4.z*wq4[8+jj] + x4.w*wq4[12+jj];
            }
        }
    }
    #pragma unroll
    for (int ii = 0; ii < 4; ii++){
        int row = row0 + ty*4 + ii;
        store4(&P[row*64 + tx*4], ap[ii][0], ap[ii][1], ap[ii][2], ap[ii][3]);
        store4(&Q[row*64 + tx*4], aq[ii][0], aq[ii][1], aq[ii][2], aq[ii][3]);
    }
}

// ---------------- PASS A: stats of h = P[j]+Q[n]; optional fused max-over-k (fp32 out) ----------------
template<bool DOMAX>
__global__ __launch_bounds__(256) void k_hstats(const float* __restrict__ P, const float* __restrict__ Q,
                                                const int* __restrict__ nbr, float* __restrict__ Xraw,
                                                double* __restrict__ dsum, double* __restrict__ dssq){
    __shared__ float sbuf[16*64];
    __shared__ float qbuf[16*64];
    int row0 = blockIdx.x * 80;                   // 80 edges = 4 points x 20
    int tx = threadIdx.x & 15, ty = threadIdx.x >> 4;
    int ng = (row0 + ty*5) / 20;
    int b  = ng >> 11;
    float4 q4 = *(const float4*)&Q[ng*64 + tx*4];
    float s[4] = {0.f,0.f,0.f,0.f}, s2[4] = {0.f,0.f,0.f,0.f};
    float m[4] = {-INFINITY,-INFINITY,-INFINITY,-INFINITY};
    #pragma unroll
    for (int ii = 0; ii < 5; ii++){
        int e = row0 + ty*5 + ii;
        int j = nbr[e];
        float4 p4 = *(const float4*)&P[((b << 11) + j)*64 + tx*4];
        float h0 = p4.x + q4.x, h1 = p4.y + q4.y, h2 = p4.z + q4.z, h3 = p4.w + q4.w;
        s[0] += h0; s[1] += h1; s[2] += h2; s[3] += h3;
        s2[0] += h0*h0; s2[1] += h1*h1; s2[2] += h2*h2; s2[3] += h3*h3;
        if (DOMAX){
            m[0] = fmaxf(m[0], h0); m[1] = fmaxf(m[1], h1);
            m[2] = fmaxf(m[2], h2); m[3] = fmaxf(m[3], h3);
        }
    }
    #pragma unroll
    for (int jj = 0; jj < 4; jj++){
        sbuf[ty*64 + tx*4 + jj] = s[jj];
        qbuf[ty*64 + tx*4 + jj] = s2[jj];
    }
    if (DOMAX){
        #pragma unroll
        for (int off = 32; off >= 16; off >>= 1){
            #pragma unroll
            for (int jj = 0; jj < 4; jj++) m[jj] = fmaxf(m[jj], __shfl_xor(m[jj], off));
        }
        int lane = threadIdx.x & 63;
        if (lane < 16){
            int pi = ty >> 2;
            store4(&Xraw[(row0/20 + pi)*64 + tx*4], m[0], m[1], m[2], m[3]);
        }
    }
    __syncthreads();
    if (threadIdx.x < 64){
        double t = 0.0;
        #pragma unroll
        for (int k = 0; k < 16; k++) t += (double)sbuf[k*64 + threadIdx.x];
        atomicAdd(&dsum[threadIdx.x], t);
    } else if (threadIdx.x < 128){
        int c = threadIdx.x - 64;
        double t = 0.0;
        #pragma unroll
        for (int k = 0; k < 16; k++) t += (double)qbuf[k*64 + c];
        atomicAdd(&dssq[c], t);
    }
}

// ---------------- PASS B: edge GEMM lrelu(bn(P[j]+Q[n])) * W^T, fused stats + max-over-k ----------------
__global__ __launch_bounds__(256) void k_edgegemm(const float* __restrict__ P, const float* __restrict__ Q,
                                                  const int* __restrict__ nbr,
                                                  const float* __restrict__ sc, const float* __restrict__ sh,
                                                  const float* __restrict__ w,
                                                  float* __restrict__ Xraw,
                                                  double* __restrict__ dsum, double* __restrict__ dssq){
    __shared__ __align__(16) float Fs[80*68];
    __shared__ __align__(16) float Ws[64*68];
    __shared__ float sbuf[16*64];
    __shared__ float qbuf[16*64];
    int row0 = blockIdx.x * 80;
    for (int i = threadIdx.x; i < 80*64; i += 256){
        int c = i & 63, r = i >> 6;
        int e  = row0 + r;
        int ng = e / 20;
        int b  = ng >> 11;
        int j  = nbr[e];
        float h = P[((b << 11) + j)*64 + c] + Q[ng*64 + c];
        Fs[r*68 + c] = lrelu(h*sc[c] + sh[c]);
    }
    for (int i = threadIdx.x; i < 64*64; i += 256){
        int c = i & 63, o = i >> 6;
        Ws[c*68 + o] = w[o*64 + c];
    }
    __syncthreads();
    int tx = threadIdx.x & 15, ty = threadIdx.x >> 4;
    float acc[5][4] = {{0.f}};
    for (int c0 = 0; c0 < 64; c0 += 4){
        float bb4[16];
        #pragma unroll
        for (int q = 0; q < 4; q++)
            *(float4*)&bb4[q*4] = *(const float4*)&Ws[(c0 + q)*68 + tx*4];
        #pragma unroll
        for (int ii = 0; ii < 5; ii++){
            float4 a4 = *(const float4*)&Fs[(ty*5 + ii)*68 + c0];
            #pragma unroll
            for (int jj = 0; jj < 4; jj++)
                acc[ii][jj] += a4.x*bb4[jj] + a4.y*bb4[4+jj] + a4.z*bb4[8+jj] + a4.w*bb4[12+jj];
        }
    }
    float m[4];
    #pragma unroll
    for (int jj = 0; jj < 4; jj++){
        sbuf[ty*64 + tx*4 + jj] = acc[0][jj] + acc[1][jj] + acc[2][jj] + acc[3][jj] + acc[4][jj];
        qbuf[ty*64 + tx*4 + jj] = acc[0][jj]*acc[0][jj] + acc[1][jj]*acc[1][jj] + acc[2][jj]*acc[2][jj]
                                + acc[3][jj]*acc[3][jj] + acc[4][jj]*acc[4][jj];
        m[jj] = fmaxf(fmaxf(fmaxf(acc[0][jj], acc[1][jj]), fmaxf(acc[2][jj], acc[3][jj])), acc[4][jj]);
    }
    #pragma unroll
    for (int off = 32; off >= 16; off >>= 1){
        #pragma unroll
        for (int jj = 0; jj < 4; jj++) m[jj] = fmaxf(m[jj], __shfl_xor(m[jj], off));
    }
    int lane = threadIdx.x & 63;
    if (lane < 16){
        int pi = ty >> 2;
        store4(&Xraw[(row0/20 + pi)*64 + tx*4], m[0], m[1], m[2], m[3]);
    }
    __syncthreads();
    if (threadIdx.x < 64){
        double t = 0.0;
        #pragma unroll
        for (int k = 0; k < 16; k++) t += (double)sbuf[k*64 + threadIdx.x];
        atomicAdd(&dsum[threadIdx.x], t);
    } else if (threadIdx.x < 128){
        int c = threadIdx.x - 64;
        double t = 0.0;
        #pragma unroll
        for (int k = 0; k < 16; k++) t += (double)qbuf[k*64 + c];
        atomicAdd(&dssq[c], t);
    }
}

// ---------------- BN finalize ----------------
__global__ void k_finalize(const double* __restrict__ dsum, const double* __restrict__ dssq,
                           const float* __restrict__ g, const float* __restrict__ b,
                           float* __restrict__ scale, float* __restrict__ shift,
                           int ch, double inv_cnt){
    int c = blockIdx.x*256 + threadIdx.x;
    if (c >= ch) return;
    double m = dsum[c] * inv_cnt;
    double v = dssq[c] * inv_cnt - m*m;
    if (v < 0.0) v = 0.0;
    float rs = (float)(1.0 / sqrt(v + 1e-5));
    float sc = g[c] * rs;
    scale[c] = sc;
    shift[c] = b[c] - (float)m*sc;
}

// ---------------- in-place bn+lrelu on (16384 x 64) fp32 ----------------
__global__ void k_bnact(float* __restrict__ X, const float* __restrict__ sc, const float* __restrict__ sh){
    int t = blockIdx.x*256 + threadIdx.x;
    int c = t & 63;
    X[t] = lrelu(X[t]*sc[c] + sh[c]);
}

// ---------------- per-row squared norm ----------------
__global__ void k_sqnorm(const float* __restrict__ X, float* __restrict__ sqn){
    int row  = blockIdx.x*4 + (threadIdx.x >> 6);
    int lane = threadIdx.x & 63;
    float v = X[row*64 + lane];
    float s = v*v;
    #pragma unroll
    for (int off = 32; off >= 1; off >>= 1) s += __shfl_xor(s, off);
    if (lane == 0) sqn[row] = s;
}

// ---------------- Gram (one batch): 128x128 tile, 8x8/thread ----------------
__global__ __launch_bounds__(256) void k_gram1(const float* __restrict__ Xb, float* __restrict__ gram){
    __shared__ __align__(16) float As[32*132];
    __shared__ __align__(16) float Bs[32*132];
    int t  = blockIdx.x;
    int tr = t >> 4, tc = t & 15;
    int tx = threadIdx.x & 15, ty = threadIdx.x >> 4;
    float acc[8][8];
    #pragma unroll
    for (int i = 0; i < 8; i++)
        #pragma unroll
        for (int j = 0; j < 8; j++) acc[i][j] = 0.f;
    for (int kc0 = 0; kc0 < 64; kc0 += 32){
        __syncthreads();
        for (int i = threadIdx.x; i < 128*32; i += 256){
            int k = i & 31, r = i >> 5;
            As[k*132 + r] = Xb[(tr*128 + r)*64 + kc0 + k];
            Bs[k*132 + r] = Xb[(tc*128 + r)*64 + kc0 + k];
        }
        __syncthreads();
        for (int k = 0; k < 32; k++){
            float4 a0 = *(const float4*)&As[k*132 + ty*8];
            float4 a1 = *(const float4*)&As[k*132 + ty*8 + 4];
            float4 b0 = *(const float4*)&Bs[k*132 + tx*8];
            float4 b1 = *(const float4*)&Bs[k*132 + tx*8 + 4];
            float av[8] = {a0.x,a0.y,a0.z,a0.w,a1.x,a1.y,a1.z,a1.w};
            float bv[8] = {b0.x,b0.y,b0.z,b0.w,b1.x,b1.y,b1.z,b1.w};
            #pragma unroll
            for (int i = 0; i < 8; i++)
                #pragma unroll
                for (int j = 0; j < 8; j++) acc[i][j] += av[i]*bv[j];
        }
    }
    #pragma unroll
    for (int i = 0; i < 8; i++){
        int row = tr*128 + ty*8 + i;
        *(float4*)&gram[row*NN + tc*128 + tx*8]     = make_float4(acc[i][0],acc[i][1],acc[i][2],acc[i][3]);
        *(float4*)&gram[row*NN + tc*128 + tx*8 + 4] = make_float4(acc[i][4],acc[i][5],acc[i][6],acc[i][7]);
    }
}

// ---------------- top-20 selection from gram row ----------------
__global__ __launch_bounds__(256) void k_knn_sel1(const float* __restrict__ gram, const float* __restrict__ sqn,
                                                  int* __restrict__ idx){
    int rb = blockIdx.x;
    int lane = threadIdx.x & 63;
    int n = rb*4 + (threadIdx.x >> 6);
    const float* grow = gram + n*NN;
    float sn = sqn[n];
    float d[32];
    #pragma unroll
    for (int j = 0; j < 32; j++){
        int m = j*64 + lane;
        d[j] = 2.f*grow[m] - sn - sqn[m];
    }
    int* orow = idx + n*KK;
    for (int it = 0; it < KK; it++){
        float bv = d[0]; int bm = lane;
        #pragma unroll
        for (int j = 1; j < 32; j++){
            if (d[j] > bv){ bv = d[j]; bm = j*64 + lane; }
        }
        #pragma unroll
        for (int off = 32; off >= 1; off >>= 1){
            float ov = __shfl_xor(bv, off);
            int   om = __shfl_xor(bm, off);
            if (ov > bv || (ov == bv && om < bm)){ bv = ov; bm = om; }
        }
        if (lane == 0) orow[it] = bm;
        if ((bm & 63) == lane) d[bm >> 6] = -INFINITY;
    }
}

// ---------------- pointwise GEMM head ----------------
// MODE 2: [x1,x2,x3] (CIN=192)  MODE 3: [gmax,x1,x2,x3] (CIN=1216)  MODE 4: bn(H7)+lrelu (CIN=512)
template<int MODE, int CIN, int COUT, bool MAXN, bool STORE, typename TST, typename TH7>
__global__ __launch_bounds__(256) void k_gemm_pt(
    const float* __restrict__ X1, const float* __restrict__ X2,
    const float* __restrict__ X3, const float* __restrict__ GM,
    const TH7*  __restrict__ H7,
    const float* __restrict__ sc_in, const float* __restrict__ sh_in,
    const float* __restrict__ w,
    TST* __restrict__ H, float* __restrict__ part,
    double* __restrict__ dsum, double* __restrict__ dssq)
{
    constexpr int CT = COUT / 64;
    __shared__ __align__(16) float Fs[64*68];
    __shared__ __align__(16) float Ws[64*68];
    __shared__ float sbuf[16*64];
    __shared__ float qbuf[16*64];
    __shared__ float mbuf[16*64];
    int rt = blockIdx.x / CT;
    int ct = blockIdx.x % CT;
    int row0 = rt * 64;
    int tx = threadIdx.x & 15, ty = threadIdx.x >> 4;
    float acc[4][4] = {{0.f}};
    for (int cg0 = 0; cg0 < CIN; cg0 += 64){
        __syncthreads();
        for (int i = threadIdx.x; i < 64*64; i += 256){
            int c = i & 63, r = i >> 6;
            int cg = cg0 + c;
            int row = row0 + r;
            float v;
            if (MODE == 2){
                v = (cg < 64) ? X1[row*64 + cg]
                    : (cg < 128 ? X2[row*64 + cg - 64] : X3[row*64 + cg - 128]);
            } else if (MODE == 3){
                if (cg < 1024){ int b = row >> 11; v = GM[(b << 10) + cg]; }
                else {
                    int f = cg - 1024;
                    v = (f < 64) ? X1[row*64 + f]
                        : (f < 128 ? X2[row*64 + f - 64] : X3[row*64 + f - 128]);
                }
            } else {
                v = lrelu((float)H7[row*512 + cg]*sc_in[cg] + sh_in[cg]);
            }
            Fs[r*68 + c] = v;
        }
        for (int i = threadIdx.x; i < 64*64; i += 256){
            int c = i & 63, o = i >> 6;
            Ws[c*68 + o] = w[(ct*64 + o)*CIN + cg0 + c];
        }
        __syncthreads();
        for (int c0 = 0; c0 < 64; c0 += 4){
            float bb4[16];
            #pragma unroll
            for (int q = 0; q < 4; q++)
                *(float4*)&bb4[q*4] = *(const float4*)&Ws[(c0 + q)*68 + tx*4];
            #pragma unroll
            for (int ii = 0; ii < 4; ii++){
                float4 a4 = *(const float4*)&Fs[(ty*4 + ii)*68 + c0];
                #pragma unroll
                for (int jj = 0; jj < 4; jj++)
                    acc[ii][jj] += a4.x*bb4[jj] + a4.y*bb4[4+jj] + a4.z*bb4[8+jj] + a4.w*bb4[12+jj];
            }
        }
    }
    if (STORE){
        #pragma unroll
        for (int ii = 0; ii < 4; ii++){
            int row = row0 + ty*4 + ii;
            store4(&H[row*COUT + ct*64 + tx*4], acc[ii][0], acc[ii][1], acc[ii][2], acc[ii][3]);
        }
    }
    #pragma unroll
    for (int jj = 0; jj < 4; jj++){
        sbuf[ty*64 + tx*4 + jj] = acc[0][jj] + acc[1][jj] + acc[2][jj] + acc[3][jj];
        qbuf[ty*64 + tx*4 + jj] = acc[0][jj]*acc[0][jj] + acc[1][jj]*acc[1][jj]
                                + acc[2][jj]*acc[2][jj] + acc[3][jj]*acc[3][jj];
        if (MAXN)
            mbuf[ty*64 + tx*4 + jj] = fmaxf(fmaxf(acc[0][jj], acc[1][jj]), fmaxf(acc[2][jj], acc[3][jj]));
    }
    __syncthreads();
    if (threadIdx.x < 64){
        double t = 0.0;
        #pragma unroll
        for (int k = 0; k < 16; k++) t += (double)sbuf[k*64 + threadIdx.x];
        atomicAdd(&dsum[ct*64 + threadIdx.x], t);
        if (MAXN){
            float mm = -INFINITY;
            #pragma unroll
            for (int k = 0; k < 16; k++) mm = fmaxf(mm, mbuf[k*64 + threadIdx.x]);
            part[rt*1024 + ct*64 + threadIdx.x] = mm;
        }
    } else if (threadIdx.x < 128){
        int c = threadIdx.x - 64;
        double t = 0.0;
        #pragma unroll
        for (int k = 0; k < 16; k++) t += (double)qbuf[k*64 + c];
        atomicAdd(&dssq[ct*64 + c], t);
    }
}

// ---------------- reduce partial maxes, apply bn6+lrelu ----------------
__global__ void k_gmax_fin(const float* __restrict__ part, const float* __restrict__ sc,
                           const float* __restrict__ sh, float* __restrict__ gmax){
    int t = blockIdx.x*256 + threadIdx.x;   // b*1024 + c
    int b = t >> 10, c = t & 1023;
    float m = -INFINITY;
    #pragma unroll
    for (int k = 0; k < 32; k++) m = fmaxf(m, part[(b*32 + k)*1024 + c]);
    gmax[t] = lrelu(m*sc[c] + sh[c]);
}

// ---------------- tier A: layer-8 recompute fused with BN8+lrelu + transpose -> out1 ----------------
template<typename TH7>
__global__ __launch_bounds__(256) void k_out8(const TH7* __restrict__ H7,
                                              const float* __restrict__ sc7, const float* __restrict__ sh7,
                                              const float* __restrict__ sc8, const float* __restrict__ sh8,
                                              const float* __restrict__ w, float* __restrict__ out1){
    constexpr int CT = 4;
    __shared__ __align__(16) float Fs[64*68];
    __shared__ __align__(16) float Ws[64*68];
    __shared__ float tile[64*65];
    int rt = blockIdx.x / CT, ct = blockIdx.x % CT;
    int row0 = rt * 64;
    int tx = threadIdx.x & 15, ty = threadIdx.x >> 4;
    float acc[4][4] = {{0.f}};
    for (int cg0 = 0; cg0 < 512; cg0 += 64){
        __syncthreads();
        for (int i = threadIdx.x; i < 64*64; i += 256){
            int c = i & 63, r = i >> 6;
            int cg = cg0 + c;
            Fs[r*68 + c] = lrelu((float)H7[(row0 + r)*512 + cg]*sc7[cg] + sh7[cg]);
        }
        for (int i = threadIdx.x; i < 64*64; i += 256){
            int c = i & 63, o = i >> 6;
            Ws[c*68 + o] = w[(ct*64 + o)*512 + cg0 + c];
        }
        __syncthreads();
        for (int c0 = 0; c0 < 64; c0 += 4){
            float bb4[16];
            #pragma unroll
            for (int q = 0; q < 4; q++)
                *(float4*)&bb4[q*4] = *(const float4*)&Ws[(c0 + q)*68 + tx*4];
            #pragma unroll
            for (int ii = 0; ii < 4; ii++){
                float4 a4 = *(const float4*)&Fs[(ty*4 + ii)*68 + c0];
                #pragma unroll
                for (int jj = 0; jj < 4; jj++)
                    acc[ii][jj] += a4.x*bb4[jj] + a4.y*bb4[4+jj] + a4.z*bb4[8+jj] + a4.w*bb4[12+jj];
            }
        }
    }
    __syncthreads();
    #pragma unroll
    for (int ii = 0; ii < 4; ii++){
        #pragma unroll
        for (int jj = 0; jj < 4; jj++){
            int oc = ct*64 + tx*4 + jj;
            tile[(tx*4 + jj)*65 + ty*4 + ii] = lrelu(acc[ii][jj]*sc8[oc] + sh8[oc]);
        }
    }
    __syncthreads();
    int b  = row0 >> 11;
    int n0 = row0 & (NN-1);
    for (int i = threadIdx.x; i < 64*64; i += 256){
        int nl = i & 63, o = i >> 6;
        out1[b*256*NN + (ct*64 + o)*NN + n0 + nl] = tile[o*65 + nl];
    }
}

// ---------------- tiers B/C: BN8+lrelu + transpose from stored H8 ----------------
template<typename TH8>
__global__ __launch_bounds__(256) void k_final(const TH8* __restrict__ H8,
                                               const float* __restrict__ scale,
                                               const float* __restrict__ shift,
                                               float* __restrict__ out1){
    __shared__ float tile[64*65];
    int bi = blockIdx.x;
    int b  = bi / 128;
    int r  = bi % 128;
    int nt = r >> 2, ot = r & 3;
    for (int i = threadIdx.x; i < 64*64; i += 256){
        int o = i & 63, nl = i >> 6;
        float v = (float)H8[((b*NN) + nt*64 + nl)*256 + ot*64 + o];
        int oc = ot*64 + o;
        tile[o*65 + nl] = lrelu(v*scale[oc] + shift[oc]);
    }
    __syncthreads();
    for (int i = threadIdx.x; i < 64*64; i += 256){
        int nl = i & 63, o = i >> 6;
        out1[b*256*NN + (ot*64 + o)*NN + nt*64 + nl] = tile[o*65 + nl];
    }
}

// ---------------- host launcher ----------------
extern "C" void kernel_launch(void* const* d_in, const int* in_sizes, int n_in,
                              void* d_out, int out_size, void* d_ws, size_t ws_size,
                              hipStream_t stream){
    const float* x = (const float*)d_in[0];
    const float *w[8], *g[8], *bb[8];
    for (int i = 0; i < 8; i++){
        w[i]  = (const float*)d_in[1 + i*3];
        g[i]  = (const float*)d_in[2 + i*3];
        bb[i] = (const float*)d_in[3 + i*3];
    }
    float* ws  = (float*)d_ws;
    float* X1  = ws + OFF_X1;
    float* X2  = ws + OFF_X2;
    float* X3  = ws + OFF_X3;
    float* SQN = ws + OFF_SQN;
    float* GMAX= ws + OFF_GMAX;
    float* PART= ws + OFF_PART;
    double* DS = (double*)(ws + OFF_STATS);
    float*  FS = ws + OFF_STATS + 8448;
    int*   IDX = (int*)(ws + OFF_IDX);

    float* out0 = (float*)d_out;
    float* out1 = out0 + BB*NN*CC;
    float* P    = out1;                            // 1048576 fl
    float* Q    = out1 + 1048576;                  // 1048576 fl
    float* GRAM = out1;                            // 4194304 fl (aliases P/Q; disjoint lifetime)

    const int chs[8]   = {64,64,64,64,64,1024,512,256};
    const int base[8]  = {0,128,256,384,512,640,2688,3712};
    double *SUMp[8], *SSQp[8];
    float  *SCp[8],  *SHp[8];
    for (int L = 0; L < 8; L++){
        SUMp[L] = DS + base[L];
        SSQp[L] = DS + base[L] + chs[L];
        SCp[L]  = FS + base[L];
        SHp[L]  = FS + base[L] + chs[L];
    }
    const double invE = 1.0 / (double)(BB*NN*KK);
    const double invP = 1.0 / (double)(BB*NN);

    hipMemsetAsync(DS, 0, 4224*sizeof(double), stream);
    k_echo<<<576,256,0,stream>>>(x, out0);

    // ---- stage 1 ----
    k_knn3<<<BB*NN/4,256,0,stream>>>(x, IDX);
    k_pq9<<<256,256,0,stream>>>(x, w[0], P, Q);
    k_hstats<false><<<4096,256,0,stream>>>(P, Q, IDX, nullptr, SUMp[0], SSQp[0]);
    k_finalize<<<1,256,0,stream>>>(SUMp[0],SSQp[0],g[0],bb[0],SCp[0],SHp[0],64,invE);
    k_edgegemm<<<4096,256,0,stream>>>(P, Q, IDX, SCp[0], SHp[0], w[1], X1, SUMp[1], SSQp[1]);
    k_finalize<<<1,256,0,stream>>>(SUMp[1],SSQp[1],g[1],bb[1],SCp[1],SHp[1],64,invE);
    k_bnact<<<4096,256,0,stream>>>(X1, SCp[1], SHp[1]);

    // ---- stage 2 ----
    k_sqnorm<<<4096,256,0,stream>>>(X1, SQN);
    for (int b = 0; b < BB; b++){
        k_gram1<<<256,256,0,stream>>>(X1 + b*NN*64, GRAM);
        k_knn_sel1<<<NN/4,256,0,stream>>>(GRAM, SQN + b*NN, IDX + b*NN*KK);
    }
    k_pq64<<<256,256,0,stream>>>(X1, w[2], P, Q);
    k_hstats<false><<<4096,256,0,stream>>>(P, Q, IDX, nullptr, SUMp[2], SSQp[2]);
    k_finalize<<<1,256,0,stream>>>(SUMp[2],SSQp[2],g[2],bb[2],SCp[2],SHp[2],64,invE);
    k_edgegemm<<<4096,256,0,stream>>>(P, Q, IDX, SCp[2], SHp[2], w[3], X2, SUMp[3], SSQp[3]);
    k_finalize<<<1,256,0,stream>>>(SUMp[3],SSQp[3],g[3],bb[3],SCp[3],SHp[3],64,invE);
    k_bnact<<<4096,256,0,stream>>>(X2, SCp[3], SHp[3]);

    // ---- stage 3 ----
    k_sqnorm<<<4096,256,0,stream>>>(X2, SQN);
    for (int b = 0; b < BB; b++){
        k_gram1<<<256,256,0,stream>>>(X2 + b*NN*64, GRAM);
        k_knn_sel1<<<NN/4,256,0,stream>>>(GRAM, SQN + b*NN, IDX + b*NN*KK);
    }
    k_pq64<<<256,256,0,stream>>>(X2, w[4], P, Q);
    k_hstats<true><<<4096,256,0,stream>>>(P, Q, IDX, X3, SUMp[4], SSQp[4]);
    k_finalize<<<1,256,0,stream>>>(SUMp[4],SSQp[4],g[4],bb[4],SCp[4],SHp[4],64,invE);
    k_bnact<<<4096,256,0,stream>>>(X3, SCp[4], SHp[4]);

    // ---- layer 6 + global max ----
    k_gemm_pt<2,192,1024,true,false,float,float><<<4096,256,0,stream>>>(
        X1,X2,X3,nullptr,(const float*)nullptr,nullptr,nullptr,w[5],(float*)nullptr,PART,SUMp[5],SSQp[5]);
    k_finalize<<<4,256,0,stream>>>(SUMp[5],SSQp[5],g[5],bb[5],SCp[5],SHp[5],1024,invP);
    k_gmax_fin<<<32,256,0,stream>>>(PART, SCp[5], SHp[5], GMAX);

    // ---- layers 7/8, tiered by ws_size ----
    if (ws_size >= (size_t)12161536*4){
        // tier A: H7 fp32 in ws; no H8 (stats + fused recompute)
        float* H7f = ws + BASE_END;
        k_gemm_pt<3,1216,512,false,true,float,float><<<2048,256,0,stream>>>(
            X1,X2,X3,GMAX,(const float*)nullptr,nullptr,nullptr,w[6],H7f,nullptr,SUMp[6],SSQp[6]);
        k_finalize<<<2,256,0,stream>>>(SUMp[6],SSQp[6],g[6],bb[6],SCp[6],SHp[6],512,invP);
        k_gemm_pt<4,512,256,false,false,float,float><<<1024,256,0,stream>>>(
            nullptr,nullptr,nullptr,nullptr,H7f,SCp[6],SHp[6],w[7],(float*)nullptr,nullptr,SUMp[7],SSQp[7]);
        k_finalize<<<1,256,0,stream>>>(SUMp[7],SSQp[7],g[7],bb[7],SCp[7],SHp[7],256,invP);
        k_out8<float><<<1024,256,0,stream>>>(H7f, SCp[6], SHp[6], SCp[7], SHp[7], w[7], out1);
    } else if (ws_size >= (size_t)7967232*4){
        // tier B: H7 bf16 in d_out, H8 fp32 in ws
        bf16*  H7b = (bf16*)out1;
        float* H8f = ws + BASE_END;
        k_gemm_pt<3,1216,512,false,true,bf16,float><<<2048,256,0,stream>>>(
            X1,X2,X3,GMAX,(const float*)nullptr,nullptr,nullptr,w[6],H7b,nullptr,SUMp[6],SSQp[6]);
        k_finalize<<<2,256,0,stream>>>(SUMp[6],SSQp[6],g[6],bb[6],SCp[6],SHp[6],512,invP);
        k_gemm_pt<4,512,256,false,true,float,bf16><<<1024,256,0,stream>>>(
            nullptr,nullptr,nullptr,nullptr,H7b,SCp[6],SHp[6],w[7],H8f,nullptr,SUMp[7],SSQp[7]);
        k_finalize<<<1,256,0,stream>>>(SUMp[7],SSQp[7],g[7],bb[7],SCp[7],SHp[7],256,invP);
        k_final<float><<<1024,256,0,stream>>>(H8f, SCp[7], SHp[7], out1);
    } else {
        // tier C: H7 bf16 in d_out, H8 bf16 aliases X1+X2
        bf16* H7b = (bf16*)out1;
        bf16* H8b = (bf16*)(ws + OFF_X1);
        k_gemm_pt<3,1216,512,false,true,bf16,float><<<2048,256,0,stream>>>(
            X1,X2,X3,GMAX,(const float*)nullptr,nullptr,nullptr,w[6],H7b,nullptr,SUMp[6],SSQp[6]);
        k_finalize<<<2,256,0,stream>>>(SUMp[6],SSQp[6],g[6],bb[6],SCp[6],SHp[6],512,invP);
        k_gemm_pt<4,512,256,false,true,bf16,bf16><<<1024,256,0,stream>>>(
            nullptr,nullptr,nullptr,nullptr,H7b,SCp[6],SHp[6],w[7],H8b,nullptr,SUMp[7],SSQp[7]);
        k_finalize<<<1,256,0,stream>>>(SUMp[7],SSQp[7],g[7],bb[7],SCp[7],SHp[7],256,invP);
        k_final<bf16><<<1024,256,0,stream>>>(H8b, SCp[7], SHp[7], out1);
    }
}

// Round 7
// 1745.124 us; speedup vs baseline: 1.2391x; 1.2391x over previous
//
#include <hip/hip_runtime.h>
#include <hip/hip_bf16.h>

typedef __hip_bfloat16 bf16;

#define BB 8
#define NN 2048
#define CC 9
#define KK 20

// ---------------- ws layout (float elements) ----------------
static constexpr int OFF_X1   = 0;               // 1048576 (16384x64 fp32)
static constexpr int OFF_X2   = 1048576;         // 1048576
static constexpr int OFF_X3   = 2097152;         // 1048576
static constexpr int OFF_SQN  = 3145728;         // 16384
static constexpr int OFF_GMAX = 3162112;         // 8192
static constexpr int OFF_PART = 3170304;         // 262144 (uses 131072; C7 at +131072)
static constexpr int OFF_STATS= 3432448;         // 12800 (4224 doubles + 4224 floats)
static constexpr int OFF_IDX  = 3445248;         // 327680 (int32)
static constexpr int BASE_END = 3772928;         // 15.1 MB
// tier A: H7 fp32 (16384x512) at BASE_END -> 48.6 MB
// tier B: H7 bf16 at BASE_END -> 31.9 MB
// tier C: H7 bf16 in d_out scratch; H8 bf16 aliases X1+X2
// d_out scratch (out1 region, 4194304 fl): P|Q, then GRAM, then (tier C) H7-bf16; finally raw-h8/out1

__device__ __forceinline__ float lrelu(float x){ return x >= 0.f ? x : 0.2f * x; }

__device__ __forceinline__ void store4(float* p, float a, float b, float c, float d){
    *(float4*)p = make_float4(a,b,c,d);
}
__device__ __forceinline__ void store4(bf16* p, float a, float b, float c, float d){
    union { bf16 h[4]; uint2 u; } pk;
    pk.h[0] = (bf16)a; pk.h[1] = (bf16)b; pk.h[2] = (bf16)c; pk.h[3] = (bf16)d;
    *(uint2*)p = pk.u;
}

// ---------------- K0: echo (B,C,N) -> (B,N,C) fp32 ----------------
__global__ void k_echo(const float* __restrict__ x, float* __restrict__ out0){
    int t = blockIdx.x * 256 + threadIdx.x;
    if (t >= BB*CC*NN) return;
    int b = t / (CC*NN); int r = t % (CC*NN); int c = r / NN; int n = r % NN;
    out0[(b*NN + n)*CC + c] = x[t];
}

// ---------------- K1: knn on 3-d coords ----------------
__global__ __launch_bounds__(256) void k_knn3(const float* __restrict__ x, int* __restrict__ idx){
    __shared__ float crd[NN*3];
    int b  = blockIdx.x / (NN/4);
    int rb = blockIdx.x % (NN/4);
    for (int c = 0; c < 3; c++)
        for (int p = threadIdx.x; p < NN; p += 256)
            crd[p*3 + c] = x[(b*CC + 6 + c)*NN + p];
    __syncthreads();
    int lane = threadIdx.x & 63;
    int n = rb*4 + (threadIdx.x >> 6);
    float qx = crd[n*3], qy = crd[n*3+1], qz = crd[n*3+2];
    float sqn = qx*qx + qy*qy + qz*qz;
    float d[32];
    #pragma unroll
    for (int j = 0; j < 32; j++){
        int m = j*64 + lane;
        float mx = crd[m*3], my = crd[m*3+1], mz = crd[m*3+2];
        d[j] = 2.f*(qx*mx + qy*my + qz*mz) - sqn - (mx*mx + my*my + mz*mz);
    }
    int* orow = idx + (b*NN + n)*KK;
    for (int it = 0; it < KK; it++){
        float bv = d[0]; int bm = lane;
        #pragma unroll
        for (int j = 1; j < 32; j++){
            if (d[j] > bv){ bv = d[j]; bm = j*64 + lane; }
        }
        #pragma unroll
        for (int off = 32; off >= 1; off >>= 1){
            float ov = __shfl_xor(bv, off);
            int   om = __shfl_xor(bm, off);
            if (ov > bv || (ov == bv && om < bm)){ bv = ov; bm = om; }
        }
        if (lane == 0) orow[it] = bm;
        if ((bm & 63) == lane) d[bm >> 6] = -INFINITY;
    }
}

// ---------------- P/Q stage 1 ----------------
__global__ __launch_bounds__(256) void k_pq9(const float* __restrict__ x, const float* __restrict__ w,
                                             float* __restrict__ P, float* __restrict__ Q){
    __shared__ __align__(16) float Xs[64*16];
    __shared__ __align__(16) float Wp[12*68];
    __shared__ __align__(16) float Wq[12*68];
    int row0 = blockIdx.x * 64;
    int b  = row0 >> 11;
    int n0 = row0 & (NN-1);
    int tx = threadIdx.x & 15, ty = threadIdx.x >> 4;
    for (int i = threadIdx.x; i < 64*12; i += 256){
        int r = i & 63, c = i >> 6;
        Xs[r*16 + c] = (c < 9) ? x[(b*CC + c)*NN + n0 + r] : 0.f;
    }
    for (int i = threadIdx.x; i < 64*12; i += 256){
        int c = i % 12, o = i / 12;
        float a = 0.f, dd = 0.f;
        if (c < 9){
            a  = w[o*18 + c];
            dd = w[o*18 + 9 + c] - a;
        }
        Wp[c*68 + o] = a;
        Wq[c*68 + o] = dd;
    }
    __syncthreads();
    float ap[4][4] = {{0.f}}, aq[4][4] = {{0.f}};
    for (int c0 = 0; c0 < 12; c0 += 4){
        float wp4[16], wq4[16];
        #pragma unroll
        for (int q = 0; q < 4; q++){
            *(float4*)&wp4[q*4] = *(const float4*)&Wp[(c0 + q)*68 + tx*4];
            *(float4*)&wq4[q*4] = *(const float4*)&Wq[(c0 + q)*68 + tx*4];
        }
        #pragma unroll
        for (int ii = 0; ii < 4; ii++){
            float4 x4 = *(const float4*)&Xs[(ty*4 + ii)*16 + c0];
            #pragma unroll
            for (int jj = 0; jj < 4; jj++){
                ap[ii][jj] += x4.x*wp4[jj] + x4.y*wp4[4+jj] + x4.z*wp4[8+jj] + x4.w*wp4[12+jj];
                aq[ii][jj] += x4.x*wq4[jj] + x4.y*wq4[4+jj] + x4.z*wq4[8+jj] + x4.w*wq4[12+jj];
            }
        }
    }
    #pragma unroll
    for (int ii = 0; ii < 4; ii++){
        int row = row0 + ty*4 + ii;
        store4(&P[row*64 + tx*4], ap[ii][0], ap[ii][1], ap[ii][2], ap[ii][3]);
        store4(&Q[row*64 + tx*4], aq[ii][0], aq[ii][1], aq[ii][2], aq[ii][3]);
    }
}

// ---------------- P/Q stages 2/3 ----------------
__global__ __launch_bounds__(256) void k_pq64(const float* __restrict__ X, const float* __restrict__ w,
                                              float* __restrict__ P, float* __restrict__ Q){
    __shared__ __align__(16) float Xs[64*68];
    __shared__ __align__(16) float Wp[64*68];
    __shared__ __align__(16) float Wq[64*68];
    int row0 = blockIdx.x * 64;
    int tx = threadIdx.x & 15, ty = threadIdx.x >> 4;
    for (int i = threadIdx.x; i < 64*64; i += 256){
        int c = i & 63, r = i >> 6;
        Xs[r*68 + c] = X[(row0 + r)*64 + c];
    }
    for (int i = threadIdx.x; i < 64*64; i += 256){
        int c = i & 63, o = i >> 6;
        float a  = w[o*128 + c];
        Wp[c*68 + o] = a;
        Wq[c*68 + o] = w[o*128 + 64 + c] - a;
    }
    __syncthreads();
    float ap[4][4] = {{0.f}}, aq[4][4] = {{0.f}};
    for (int c0 = 0; c0 < 64; c0 += 4){
        float wp4[16], wq4[16];
        #pragma unroll
        for (int q = 0; q < 4; q++){
            *(float4*)&wp4[q*4] = *(const float4*)&Wp[(c0 + q)*68 + tx*4];
            *(float4*)&wq4[q*4] = *(const float4*)&Wq[(c0 + q)*68 + tx*4];
        }
        #pragma unroll
        for (int ii = 0; ii < 4; ii++){
            float4 x4 = *(const float4*)&Xs[(ty*4 + ii)*68 + c0];
            #pragma unroll
            for (int jj = 0; jj < 4; jj++){
                ap[ii][jj] += x4.x*wp4[jj] + x4.y*wp4[4+jj] + x4.z*wp4[8+jj] + x4.w*wp4[12+jj];
                aq[ii][jj] += x4.x*wq4[jj] + x4.y*wq4[4+jj] + x4.z*wq4[8+jj] + x4.w*wq4[12+jj];
            }
        }
    }
    #pragma unroll
    for (int ii = 0; ii < 4; ii++){
        int row = row0 + ty*4 + ii;
        store4(&P[row*64 + tx*4], ap[ii][0], ap[ii][1], ap[ii][2], ap[ii][3]);
        store4(&Q[row*64 + tx*4], aq[ii][0], aq[ii][1], aq[ii][2], aq[ii][3]);
    }
}

// ---------------- PASS A: stats of h = P[j]+Q[n]; optional fused max-over-k ----------------
template<bool DOMAX>
__global__ __launch_bounds__(256) void k_hstats(const float* __restrict__ P, const float* __restrict__ Q,
                                                const int* __restrict__ nbr, float* __restrict__ Xraw,
                                                double* __restrict__ dsum, double* __restrict__ dssq){
    __shared__ float sbuf[16*64];
    __shared__ float qbuf[16*64];
    int row0 = blockIdx.x * 80;
    int tx = threadIdx.x & 15, ty = threadIdx.x >> 4;
    int ng = (row0 + ty*5) / 20;
    int b  = ng >> 11;
    float4 q4 = *(const float4*)&Q[ng*64 + tx*4];
    float s[4] = {0.f,0.f,0.f,0.f}, s2[4] = {0.f,0.f,0.f,0.f};
    float m[4] = {-INFINITY,-INFINITY,-INFINITY,-INFINITY};
    #pragma unroll
    for (int ii = 0; ii < 5; ii++){
        int e = row0 + ty*5 + ii;
        int j = nbr[e];
        float4 p4 = *(const float4*)&P[((b << 11) + j)*64 + tx*4];
        float h0 = p4.x + q4.x, h1 = p4.y + q4.y, h2 = p4.z + q4.z, h3 = p4.w + q4.w;
        s[0] += h0; s[1] += h1; s[2] += h2; s[3] += h3;
        s2[0] += h0*h0; s2[1] += h1*h1; s2[2] += h2*h2; s2[3] += h3*h3;
        if (DOMAX){
            m[0] = fmaxf(m[0], h0); m[1] = fmaxf(m[1], h1);
            m[2] = fmaxf(m[2], h2); m[3] = fmaxf(m[3], h3);
        }
    }
    #pragma unroll
    for (int jj = 0; jj < 4; jj++){
        sbuf[ty*64 + tx*4 + jj] = s[jj];
        qbuf[ty*64 + tx*4 + jj] = s2[jj];
    }
    if (DOMAX){
        #pragma unroll
        for (int off = 32; off >= 16; off >>= 1){
            #pragma unroll
            for (int jj = 0; jj < 4; jj++) m[jj] = fmaxf(m[jj], __shfl_xor(m[jj], off));
        }
        int lane = threadIdx.x & 63;
        if (lane < 16){
            int pi = ty >> 2;
            store4(&Xraw[(row0/20 + pi)*64 + tx*4], m[0], m[1], m[2], m[3]);
        }
    }
    __syncthreads();
    if (threadIdx.x < 64){
        double t = 0.0;
        #pragma unroll
        for (int k = 0; k < 16; k++) t += (double)sbuf[k*64 + threadIdx.x];
        atomicAdd(&dsum[threadIdx.x], t);
    } else if (threadIdx.x < 128){
        int c = threadIdx.x - 64;
        double t = 0.0;
        #pragma unroll
        for (int k = 0; k < 16; k++) t += (double)qbuf[k*64 + c];
        atomicAdd(&dssq[c], t);
    }
}

// ---------------- PASS B: edge GEMM, fused stats + max-over-k ----------------
__global__ __launch_bounds__(256) void k_edgegemm(const float* __restrict__ P, const float* __restrict__ Q,
                                                  const int* __restrict__ nbr,
                                                  const float* __restrict__ sc, const float* __restrict__ sh,
                                                  const float* __restrict__ w,
                                                  float* __restrict__ Xraw,
                                                  double* __restrict__ dsum, double* __restrict__ dssq){
    __shared__ __align__(16) float Fs[80*68];
    __shared__ __align__(16) float Ws[64*68];
    __shared__ float sbuf[16*64];
    __shared__ float qbuf[16*64];
    int row0 = blockIdx.x * 80;
    for (int i = threadIdx.x; i < 80*64; i += 256){
        int c = i & 63, r = i >> 6;
        int e  = row0 + r;
        int ng = e / 20;
        int b  = ng >> 11;
        int j  = nbr[e];
        float h = P[((b << 11) + j)*64 + c] + Q[ng*64 + c];
        Fs[r*68 + c] = lrelu(h*sc[c] + sh[c]);
    }
    for (int i = threadIdx.x; i < 64*64; i += 256){
        int c = i & 63, o = i >> 6;
        Ws[c*68 + o] = w[o*64 + c];
    }
    __syncthreads();
    int tx = threadIdx.x & 15, ty = threadIdx.x >> 4;
    float acc[5][4] = {{0.f}};
    for (int c0 = 0; c0 < 64; c0 += 4){
        float bb4[16];
        #pragma unroll
        for (int q = 0; q < 4; q++)
            *(float4*)&bb4[q*4] = *(const float4*)&Ws[(c0 + q)*68 + tx*4];
        #pragma unroll
        for (int ii = 0; ii < 5; ii++){
            float4 a4 = *(const float4*)&Fs[(ty*5 + ii)*68 + c0];
            #pragma unroll
            for (int jj = 0; jj < 4; jj++)
                acc[ii][jj] += a4.x*bb4[jj] + a4.y*bb4[4+jj] + a4.z*bb4[8+jj] + a4.w*bb4[12+jj];
        }
    }
    float m[4];
    #pragma unroll
    for (int jj = 0; jj < 4; jj++){
        sbuf[ty*64 + tx*4 + jj] = acc[0][jj] + acc[1][jj] + acc[2][jj] + acc[3][jj] + acc[4][jj];
        qbuf[ty*64 + tx*4 + jj] = acc[0][jj]*acc[0][jj] + acc[1][jj]*acc[1][jj] + acc[2][jj]*acc[2][jj]
                                + acc[3][jj]*acc[3][jj] + acc[4][jj]*acc[4][jj];
        m[jj] = fmaxf(fmaxf(fmaxf(acc[0][jj], acc[1][jj]), fmaxf(acc[2][jj], acc[3][jj])), acc[4][jj]);
    }
    #pragma unroll
    for (int off = 32; off >= 16; off >>= 1){
        #pragma unroll
        for (int jj = 0; jj < 4; jj++) m[jj] = fmaxf(m[jj], __shfl_xor(m[jj], off));
    }
    int lane = threadIdx.x & 63;
    if (lane < 16){
        int pi = ty >> 2;
        store4(&Xraw[(row0/20 + pi)*64 + tx*4], m[0], m[1], m[2], m[3]);
    }
    __syncthreads();
    if (threadIdx.x < 64){
        double t = 0.0;
        #pragma unroll
        for (int k = 0; k < 16; k++) t += (double)sbuf[k*64 + threadIdx.x];
        atomicAdd(&dsum[threadIdx.x], t);
    } else if (threadIdx.x < 128){
        int c = threadIdx.x - 64;
        double t = 0.0;
        #pragma unroll
        for (int k = 0; k < 16; k++) t += (double)qbuf[k*64 + c];
        atomicAdd(&dssq[c], t);
    }
}

// ---------------- BN finalize ----------------
__global__ void k_finalize(const double* __restrict__ dsum, const double* __restrict__ dssq,
                           const float* __restrict__ g, const float* __restrict__ b,
                           float* __restrict__ scale, float* __restrict__ shift,
                           int ch, double inv_cnt){
    int c = blockIdx.x*256 + threadIdx.x;
    if (c >= ch) return;
    double m = dsum[c] * inv_cnt;
    double v = dssq[c] * inv_cnt - m*m;
    if (v < 0.0) v = 0.0;
    float rs = (float)(1.0 / sqrt(v + 1e-5));
    float sc = g[c] * rs;
    scale[c] = sc;
    shift[c] = b[c] - (float)m*sc;
}

// ---------------- in-place bn+lrelu on (16384 x 64) ----------------
__global__ void k_bnact(float* __restrict__ X, const float* __restrict__ sc, const float* __restrict__ sh){
    int t = blockIdx.x*256 + threadIdx.x;
    int c = t & 63;
    X[t] = lrelu(X[t]*sc[c] + sh[c]);
}

// ---------------- in-place bn8+lrelu on out1 (B,256,N) ----------------
__global__ void k_bnact8(float* __restrict__ O, const float* __restrict__ sc, const float* __restrict__ sh){
    int t = blockIdx.x*256 + threadIdx.x;
    int oc = (t >> 11) & 255;
    O[t] = lrelu(O[t]*sc[oc] + sh[oc]);
}

// ---------------- per-row squared norm ----------------
__global__ void k_sqnorm(const float* __restrict__ X, float* __restrict__ sqn){
    int row  = blockIdx.x*4 + (threadIdx.x >> 6);
    int lane = threadIdx.x & 63;
    float v = X[row*64 + lane];
    float s = v*v;
    #pragma unroll
    for (int off = 32; off >= 1; off >>= 1) s += __shfl_xor(s, off);
    if (lane == 0) sqn[row] = s;
}

// ---------------- Gram (one batch): 128x128 tile, 8x8/thread ----------------
__global__ __launch_bounds__(256) void k_gram1(const float* __restrict__ Xb, float* __restrict__ gram){
    __shared__ __align__(16) float As[32*132];
    __shared__ __align__(16) float Bs[32*132];
    int t  = blockIdx.x;
    int tr = t >> 4, tc = t & 15;
    int tx = threadIdx.x & 15, ty = threadIdx.x >> 4;
    float acc[8][8];
    #pragma unroll
    for (int i = 0; i < 8; i++)
        #pragma unroll
        for (int j = 0; j < 8; j++) acc[i][j] = 0.f;
    for (int kc0 = 0; kc0 < 64; kc0 += 32){
        __syncthreads();
        for (int i = threadIdx.x; i < 128*32; i += 256){
            int k = i & 31, r = i >> 5;
            As[k*132 + r] = Xb[(tr*128 + r)*64 + kc0 + k];
            Bs[k*132 + r] = Xb[(tc*128 + r)*64 + kc0 + k];
        }
        __syncthreads();
        for (int k = 0; k < 32; k++){
            float4 a0 = *(const float4*)&As[k*132 + ty*8];
            float4 a1 = *(const float4*)&As[k*132 + ty*8 + 4];
            float4 b0 = *(const float4*)&Bs[k*132 + tx*8];
            float4 b1 = *(const float4*)&Bs[k*132 + tx*8 + 4];
            float av[8] = {a0.x,a0.y,a0.z,a0.w,a1.x,a1.y,a1.z,a1.w};
            float bv[8] = {b0.x,b0.y,b0.z,b0.w,b1.x,b1.y,b1.z,b1.w};
            #pragma unroll
            for (int i = 0; i < 8; i++)
                #pragma unroll
                for (int j = 0; j < 8; j++) acc[i][j] += av[i]*bv[j];
        }
    }
    #pragma unroll
    for (int i = 0; i < 8; i++){
        int row = tr*128 + ty*8 + i;
        *(float4*)&gram[row*NN + tc*128 + tx*8]     = make_float4(acc[i][0],acc[i][1],acc[i][2],acc[i][3]);
        *(float4*)&gram[row*NN + tc*128 + tx*8 + 4] = make_float4(acc[i][4],acc[i][5],acc[i][6],acc[i][7]);
    }
}

// ---------------- top-20 selection from gram row ----------------
__global__ __launch_bounds__(256) void k_knn_sel1(const float* __restrict__ gram, const float* __restrict__ sqn,
                                                  int* __restrict__ idx){
    int rb = blockIdx.x;
    int lane = threadIdx.x & 63;
    int n = rb*4 + (threadIdx.x >> 6);
    const float* grow = gram + n*NN;
    float sn = sqn[n];
    float d[32];
    #pragma unroll
    for (int j = 0; j < 32; j++){
        int m = j*64 + lane;
        d[j] = 2.f*grow[m] - sn - sqn[m];
    }
    int* orow = idx + n*KK;
    for (int it = 0; it < KK; it++){
        float bv = d[0]; int bm = lane;
        #pragma unroll
        for (int j = 1; j < 32; j++){
            if (d[j] > bv){ bv = d[j]; bm = j*64 + lane; }
        }
        #pragma unroll
        for (int off = 32; off >= 1; off >>= 1){
            float ov = __shfl_xor(bv, off);
            int   om = __shfl_xor(bm, off);
            if (ov > bv || (ov == bv && om < bm)){ bv = ov; bm = om; }
        }
        if (lane == 0) orow[it] = bm;
        if ((bm & 63) == lane) d[bm >> 6] = -INFINITY;
    }
}

// ---------------- C7 precompute: C7[b][oc] = sum_{c<1024} gmax[b,c] * w7[oc,c] ----------------
__global__ __launch_bounds__(256) void k_c7(const float* __restrict__ gmax, const float* __restrict__ w7,
                                            float* __restrict__ C7){
    int oc = blockIdx.x;
    int tid = threadIdx.x;
    __shared__ float red[256];
    float a[8];
    #pragma unroll
    for (int b = 0; b < 8; b++) a[b] = 0.f;
    for (int k = tid; k < 1024; k += 256){
        float wv = w7[oc*1216 + k];
        #pragma unroll
        for (int b = 0; b < 8; b++) a[b] += gmax[b*1024 + k] * wv;
    }
    for (int b = 0; b < 8; b++){
        red[tid] = a[b];
        __syncthreads();
        for (int s = 128; s > 0; s >>= 1){
            if (tid < s) red[tid] += red[tid + s];
            __syncthreads();
        }
        if (tid == 0) C7[b*512 + oc] = red[0];
        __syncthreads();
    }
}

// ---------------- unified head GEMM: 128x128 tile, 8x8/thread, stats; optional maxN/bias/store ----------------
// MODE 2: feat=[x1|x2|x3], w6 (COUT=1024), MAXN
// MODE 3: feat=[x1|x2|x3], w7 cols 1024.. (COUT=512), +C7 bias, store H7
// MODE 4: feat=bn7+lrelu(H7) (COUT=256), store raw h8 (transposed fp32 or row-major)
// STMODE: 0 none, 1 row-major (stride COUT) to HST, 2 transposed fp32 to out1t
template<int MODE, bool MAXN, int STMODE, typename TST, typename TH7>
__global__ __launch_bounds__(256) void k_head(
    const float* __restrict__ X1, const float* __restrict__ X2, const float* __restrict__ X3,
    const TH7*  __restrict__ H7, const float* __restrict__ C7,
    const float* __restrict__ sc_in, const float* __restrict__ sh_in,
    const float* __restrict__ w,
    TST* __restrict__ HST, float* __restrict__ out1t, float* __restrict__ part,
    double* __restrict__ dsum, double* __restrict__ dssq)
{
    constexpr int CIN  = (MODE == 4) ? 512 : 192;
    constexpr int WST  = (MODE == 2) ? 192 : (MODE == 3 ? 1216 : 512);
    constexpr int WOFF = (MODE == 3) ? 1024 : 0;
    constexpr int COUT = (MODE == 2) ? 1024 : (MODE == 3 ? 512 : 256);
    __shared__ __align__(16) float As[32*132];
    __shared__ __align__(16) float Bs[32*132];
    int tid = threadIdx.x;
    int rt = blockIdx.x & 127;
    int ct = blockIdx.x >> 7;
    int row0 = rt * 128;
    int col0 = ct * 128;
    int b = row0 >> 11;
    int tx = tid & 15, ty = tid >> 4;
    float acc[8][8];
    #pragma unroll
    for (int i = 0; i < 8; i++)
        #pragma unroll
        for (int j = 0; j < 8; j++) acc[i][j] = 0.f;
    for (int s = 0; s < CIN/32; s++){
        int cg0 = s*32;
        float scv = 0.f, shv = 0.f;
        if (MODE == 4){ scv = sc_in[cg0 + (tid & 31)]; shv = sh_in[cg0 + (tid & 31)]; }
        __syncthreads();
        for (int i = tid; i < 128*32; i += 256){
            int k = i & 31, r = i >> 5;
            float v;
            if (MODE == 4){
                v = lrelu((float)H7[(row0 + r)*512 + cg0 + k]*scv + shv);
            } else {
                const float* S = (cg0 < 64) ? X1 : (cg0 < 128 ? X2 : X3);
                int co = cg0 & 63;
                v = S[(row0 + r)*64 + co + k];
            }
            As[k*132 + r] = v;
        }
        for (int i = tid; i < 128*32; i += 256){
            int k = i & 31, n = i >> 5;
            Bs[k*132 + n] = w[(col0 + n)*WST + WOFF + cg0 + k];
        }
        __syncthreads();
        for (int k = 0; k < 32; k++){
            float4 a0 = *(const float4*)&As[k*132 + ty*8];
            float4 a1 = *(const float4*)&As[k*132 + ty*8 + 4];
            float4 b0 = *(const float4*)&Bs[k*132 + tx*8];
            float4 b1 = *(const float4*)&Bs[k*132 + tx*8 + 4];
            float av[8] = {a0.x,a0.y,a0.z,a0.w,a1.x,a1.y,a1.z,a1.w};
            float bv[8] = {b0.x,b0.y,b0.z,b0.w,b1.x,b1.y,b1.z,b1.w};
            #pragma unroll
            for (int i = 0; i < 8; i++)
                #pragma unroll
                for (int j = 0; j < 8; j++) acc[i][j] += av[i]*bv[j];
        }
    }
    if (MODE == 3){
        #pragma unroll
        for (int j = 0; j < 8; j++){
            float c7 = C7[b*512 + col0 + tx*8 + j];
            #pragma unroll
            for (int i = 0; i < 8; i++) acc[i][j] += c7;
        }
    }
    // store
    if (STMODE == 1){
        #pragma unroll
        for (int i = 0; i < 8; i++){
            int row = row0 + ty*8 + i;
            store4(&HST[row*COUT + col0 + tx*8],     acc[i][0], acc[i][1], acc[i][2], acc[i][3]);
            store4(&HST[row*COUT + col0 + tx*8 + 4], acc[i][4], acc[i][5], acc[i][6], acc[i][7]);
        }
    } else if (STMODE == 2){
        int n0 = (row0 & (NN-1)) + ty*8;
        #pragma unroll
        for (int j = 0; j < 8; j++){
            float* o = out1t + b*256*NN + (col0 + tx*8 + j)*NN + n0;
            *(float4*)o       = make_float4(acc[0][j], acc[1][j], acc[2][j], acc[3][j]);
            *(float4*)(o + 4) = make_float4(acc[4][j], acc[5][j], acc[6][j], acc[7][j]);
        }
    }
    // stats (overlay reduction buffers on As/Bs)
    __syncthreads();
    float* sbuf = As;            // 16*128
    float* qbuf = As + 2048;     // 16*128
    float* mbuf = Bs;            // 16*128
    #pragma unroll
    for (int j = 0; j < 8; j++){
        float sv = 0.f, qv = 0.f, mv = -INFINITY;
        #pragma unroll
        for (int i = 0; i < 8; i++){
            sv += acc[i][j];
            qv += acc[i][j]*acc[i][j];
            if (MAXN) mv = fmaxf(mv, acc[i][j]);
        }
        sbuf[ty*128 + tx*8 + j] = sv;
        qbuf[ty*128 + tx*8 + j] = qv;
        if (MAXN) mbuf[ty*128 + tx*8 + j] = mv;
    }
    __syncthreads();
    if (tid < 128){
        double t = 0.0;
        #pragma unroll
        for (int k = 0; k < 16; k++) t += (double)sbuf[k*128 + tid];
        atomicAdd(&dsum[col0 + tid], t);
        if (MAXN){
            float mm = -INFINITY;
            #pragma unroll
            for (int k = 0; k < 16; k++) mm = fmaxf(mm, mbuf[k*128 + tid]);
            part[rt*1024 + col0 + tid] = mm;
        }
    } else {
        int c = tid - 128;
        double t = 0.0;
        #pragma unroll
        for (int k = 0; k < 16; k++) t += (double)qbuf[k*128 + c];
        atomicAdd(&dssq[col0 + c], t);
    }
}

// ---------------- reduce partial maxes, apply bn6+lrelu ----------------
__global__ void k_gmax_fin(const float* __restrict__ part, const float* __restrict__ sc,
                           const float* __restrict__ sh, float* __restrict__ gmax){
    int t = blockIdx.x*256 + threadIdx.x;   // b*1024 + c
    int b = t >> 10, c = t & 1023;
    float m = -INFINITY;
    #pragma unroll
    for (int k = 0; k < 16; k++) m = fmaxf(m, part[(b*16 + k)*1024 + c]);
    gmax[t] = lrelu(m*sc[c] + sh[c]);
}

// ---------------- tier C: BN8+lrelu + transpose from stored H8 bf16 ----------------
__global__ __launch_bounds__(256) void k_final_b(const bf16* __restrict__ H8,
                                                 const float* __restrict__ scale,
                                                 const float* __restrict__ shift,
                                                 float* __restrict__ out1){
    __shared__ float tile[64*65];
    int bi = blockIdx.x;
    int b  = bi / 128;
    int r  = bi % 128;
    int nt = r >> 2, ot = r & 3;
    for (int i = threadIdx.x; i < 64*64; i += 256){
        int o = i & 63, nl = i >> 6;
        float v = (float)H8[((b*NN) + nt*64 + nl)*256 + ot*64 + o];
        int oc = ot*64 + o;
        tile[o*65 + nl] = lrelu(v*scale[oc] + shift[oc]);
    }
    __syncthreads();
    for (int i = threadIdx.x; i < 64*64; i += 256){
        int nl = i & 63, o = i >> 6;
        out1[b*256*NN + (ot*64 + o)*NN + nt*64 + nl] = tile[o*65 + nl];
    }
}

// ---------------- host launcher ----------------
extern "C" void kernel_launch(void* const* d_in, const int* in_sizes, int n_in,
                              void* d_out, int out_size, void* d_ws, size_t ws_size,
                              hipStream_t stream){
    const float* x = (const float*)d_in[0];
    const float *w[8], *g[8], *bb[8];
    for (int i = 0; i < 8; i++){
        w[i]  = (const float*)d_in[1 + i*3];
        g[i]  = (const float*)d_in[2 + i*3];
        bb[i] = (const float*)d_in[3 + i*3];
    }
    float* ws  = (float*)d_ws;
    float* X1  = ws + OFF_X1;
    float* X2  = ws + OFF_X2;
    float* X3  = ws + OFF_X3;
    float* SQN = ws + OFF_SQN;
    float* GMAX= ws + OFF_GMAX;
    float* PART= ws + OFF_PART;
    float* C7  = ws + OFF_PART + 131072;
    double* DS = (double*)(ws + OFF_STATS);
    float*  FS = ws + OFF_STATS + 8448;
    int*   IDX = (int*)(ws + OFF_IDX);

    float* out0 = (float*)d_out;
    float* out1 = out0 + BB*NN*CC;
    float* P    = out1;
    float* Q    = out1 + 1048576;
    float* GRAM = out1;

    const int chs[8]   = {64,64,64,64,64,1024,512,256};
    const int base[8]  = {0,128,256,384,512,640,2688,3712};
    double *SUMp[8], *SSQp[8];
    float  *SCp[8],  *SHp[8];
    for (int L = 0; L < 8; L++){
        SUMp[L] = DS + base[L];
        SSQp[L] = DS + base[L] + chs[L];
        SCp[L]  = FS + base[L];
        SHp[L]  = FS + base[L] + chs[L];
    }
    const double invE = 1.0 / (double)(BB*NN*KK);
    const double invP = 1.0 / (double)(BB*NN);

    hipMemsetAsync(DS, 0, 4224*sizeof(double), stream);
    k_echo<<<576,256,0,stream>>>(x, out0);

    // ---- stage 1 ----
    k_knn3<<<BB*NN/4,256,0,stream>>>(x, IDX);
    k_pq9<<<256,256,0,stream>>>(x, w[0], P, Q);
    k_hstats<false><<<4096,256,0,stream>>>(P, Q, IDX, nullptr, SUMp[0], SSQp[0]);
    k_finalize<<<1,256,0,stream>>>(SUMp[0],SSQp[0],g[0],bb[0],SCp[0],SHp[0],64,invE);
    k_edgegemm<<<4096,256,0,stream>>>(P, Q, IDX, SCp[0], SHp[0], w[1], X1, SUMp[1], SSQp[1]);
    k_finalize<<<1,256,0,stream>>>(SUMp[1],SSQp[1],g[1],bb[1],SCp[1],SHp[1],64,invE);
    k_bnact<<<4096,256,0,stream>>>(X1, SCp[1], SHp[1]);

    // ---- stage 2 ----
    k_sqnorm<<<4096,256,0,stream>>>(X1, SQN);
    for (int b = 0; b < BB; b++){
        k_gram1<<<256,256,0,stream>>>(X1 + b*NN*64, GRAM);
        k_knn_sel1<<<NN/4,256,0,stream>>>(GRAM, SQN + b*NN, IDX + b*NN*KK);
    }
    k_pq64<<<256,256,0,stream>>>(X1, w[2], P, Q);
    k_hstats<false><<<4096,256,0,stream>>>(P, Q, IDX, nullptr, SUMp[2], SSQp[2]);
    k_finalize<<<1,256,0,stream>>>(SUMp[2],SSQp[2],g[2],bb[2],SCp[2],SHp[2],64,invE);
    k_edgegemm<<<4096,256,0,stream>>>(P, Q, IDX, SCp[2], SHp[2], w[3], X2, SUMp[3], SSQp[3]);
    k_finalize<<<1,256,0,stream>>>(SUMp[3],SSQp[3],g[3],bb[3],SCp[3],SHp[3],64,invE);
    k_bnact<<<4096,256,0,stream>>>(X2, SCp[3], SHp[3]);

    // ---- stage 3 ----
    k_sqnorm<<<4096,256,0,stream>>>(X2, SQN);
    for (int b = 0; b < BB; b++){
        k_gram1<<<256,256,0,stream>>>(X2 + b*NN*64, GRAM);
        k_knn_sel1<<<NN/4,256,0,stream>>>(GRAM, SQN + b*NN, IDX + b*NN*KK);
    }
    k_pq64<<<256,256,0,stream>>>(X2, w[4], P, Q);
    k_hstats<true><<<4096,256,0,stream>>>(P, Q, IDX, X3, SUMp[4], SSQp[4]);
    k_finalize<<<1,256,0,stream>>>(SUMp[4],SSQp[4],g[4],bb[4],SCp[4],SHp[4],64,invE);
    k_bnact<<<4096,256,0,stream>>>(X3, SCp[4], SHp[4]);

    // ---- layer 6 + global max ----
    k_head<2,true,0,float,float><<<1024,256,0,stream>>>(
        X1,X2,X3,(const float*)nullptr,nullptr,nullptr,nullptr,w[5],
        (float*)nullptr,nullptr,PART,SUMp[5],SSQp[5]);
    k_finalize<<<4,256,0,stream>>>(SUMp[5],SSQp[5],g[5],bb[5],SCp[5],SHp[5],1024,invP);
    k_gmax_fin<<<32,256,0,stream>>>(PART, SCp[5], SHp[5], GMAX);
    k_c7<<<512,256,0,stream>>>(GMAX, w[6], C7);

    // ---- layers 7/8, tiered by ws_size ----
    if (ws_size >= (size_t)12161536*4){
        // tier A: H7 fp32 in ws; raw h8 transposed into out1 + in-place bn
        float* H7f = ws + BASE_END;
        k_head<3,false,1,float,float><<<512,256,0,stream>>>(
            X1,X2,X3,(const float*)nullptr,C7,nullptr,nullptr,w[6],
            H7f,nullptr,nullptr,SUMp[6],SSQp[6]);
        k_finalize<<<2,256,0,stream>>>(SUMp[6],SSQp[6],g[6],bb[6],SCp[6],SHp[6],512,invP);
        k_head<4,false,2,float,float><<<256,256,0,stream>>>(
            nullptr,nullptr,nullptr,H7f,nullptr,SCp[6],SHp[6],w[7],
            (float*)nullptr,out1,nullptr,SUMp[7],SSQp[7]);
        k_finalize<<<1,256,0,stream>>>(SUMp[7],SSQp[7],g[7],bb[7],SCp[7],SHp[7],256,invP);
        k_bnact8<<<16384,256,0,stream>>>(out1, SCp[7], SHp[7]);
    } else if (ws_size >= (size_t)7967232*4){
        // tier B: H7 bf16 in ws; raw h8 transposed into out1 + in-place bn
        bf16* H7b = (bf16*)(ws + BASE_END);
        k_head<3,false,1,bf16,float><<<512,256,0,stream>>>(
            X1,X2,X3,(const float*)nullptr,C7,nullptr,nullptr,w[6],
            H7b,nullptr,nullptr,SUMp[6],SSQp[6]);
        k_finalize<<<2,256,0,stream>>>(SUMp[6],SSQp[6],g[6],bb[6],SCp[6],SHp[6],512,invP);
        k_head<4,false,2,float,bf16><<<256,256,0,stream>>>(
            nullptr,nullptr,nullptr,H7b,nullptr,SCp[6],SHp[6],w[7],
            (float*)nullptr,out1,nullptr,SUMp[7],SSQp[7]);
        k_finalize<<<1,256,0,stream>>>(SUMp[7],SSQp[7],g[7],bb[7],SCp[7],SHp[7],256,invP);
        k_bnact8<<<16384,256,0,stream>>>(out1, SCp[7], SHp[7]);
    } else {
        // tier C: H7 bf16 in d_out scratch; H8 bf16 aliases X1+X2; old final transpose
        bf16* H7b = (bf16*)out1;
        bf16* H8b = (bf16*)(ws + OFF_X1);
        k_head<3,false,1,bf16,float><<<512,256,0,stream>>>(
            X1,X2,X3,(const float*)nullptr,C7,nullptr,nullptr,w[6],
            H7b,nullptr,nullptr,SUMp[6],SSQp[6]);
        k_finalize<<<2,256,0,stream>>>(SUMp[6],SSQp[6],g[6],bb[6],SCp[6],SHp[6],512,invP);
        k_head<4,false,1,bf16,bf16><<<256,256,0,stream>>>(
            nullptr,nullptr,nullptr,H7b,nullptr,SCp[6],SHp[6],w[7],
            H8b,nullptr,nullptr,SUMp[7],SSQp[7]);
        k_finalize<<<1,256,0,stream>>>(SUMp[7],SSQp[7],g[7],bb[7],SCp[7],SHp[7],256,invP);
        k_final_b<<<1024,256,0,stream>>>(H8b, SCp[7], SHp[7], out1);
    }
}

// Round 8
// 1501.242 us; speedup vs baseline: 1.4404x; 1.1625x over previous
//
#include <hip/hip_runtime.h>
#include <hip/hip_bf16.h>

typedef __hip_bfloat16 bf16;

#define BB 8
#define NN 2048
#define CC 9
#define KK 20

// ---------------- ws layout (float elements) ----------------
static constexpr int OFF_X1   = 0;               // 1048576 (16384x64 fp32)
static constexpr int OFF_X2   = 1048576;         // 1048576
static constexpr int OFF_X3   = 2097152;         // 1048576
static constexpr int OFF_SQN  = 3145728;         // 16384
static constexpr int OFF_GMAX = 3162112;         // 8192
static constexpr int OFF_PART = 3170304;         // 262144 (uses 131072; C7 at +131072)
static constexpr int OFF_STATS= 3432448;         // 12800 (4224 doubles + 4224 floats)
static constexpr int OFF_IDX  = 3445248;         // 327680 (int32)
static constexpr int BASE_END = 3772928;         // 15.1 MB
// BASE_END region (lifetimes disjoint): GRAM1 fp32 16MB (knn stages) | H7 (layer 7+)
// tier A: H7 fp32 (16384x512) -> needs 48.6 MB ; tier B: H7 bf16 -> 31.9 MB ; tier C: H7 bf16 in d_out
// d_out scratch (out1 region, 4194304 fl): P|Q, GRAM0, (tier C) H7-bf16; finally raw-h8/out1

__device__ __forceinline__ float lrelu(float x){ return x >= 0.f ? x : 0.2f * x; }

__device__ __forceinline__ void store4(float* p, float a, float b, float c, float d){
    *(float4*)p = make_float4(a,b,c,d);
}
__device__ __forceinline__ void store4(bf16* p, float a, float b, float c, float d){
    union { bf16 h[4]; uint2 u; } pk;
    pk.h[0] = (bf16)a; pk.h[1] = (bf16)b; pk.h[2] = (bf16)c; pk.h[3] = (bf16)d;
    *(uint2*)p = pk.u;
}

// float -> order-preserving uint32
__device__ __forceinline__ unsigned f2sort(float f){
    unsigned b = __float_as_uint(f);
    return b ^ (unsigned)(((int)b >> 31) | (int)0x80000000);
}

// ---------------- exact top-20 (largest) of 2048 candidates, one wave ----------------
// u[32]: lane's candidates, global index of u[j] = j*64 + lane.
// hist: wave-private 256 x u32 LDS. orow: 20 ints out.
// Emits orow in (descending value, ascending index) order == old extraction order.
__device__ __forceinline__ void topk20(unsigned (&u)[32], int lane, unsigned* hist, int* __restrict__ orow){
    unsigned prefix = 0;
    int need = KK;
    #pragma unroll
    for (int pass = 0; pass < 4; pass++){
        const int sh = 24 - pass*8;
        #pragma unroll
        for (int q = 0; q < 4; q++) hist[lane + q*64] = 0u;
        #pragma unroll
        for (int j = 0; j < 32; j++){
            bool ok = (pass == 0) ? true : ((u[j] >> (sh + 8)) == (prefix >> (sh + 8)));
            if (ok) atomicAdd(&hist[(u[j] >> sh) & 255u], 1u);
        }
        __syncthreads();
        uint4 hv = *(uint4*)&hist[lane*4];
        unsigned lsum = hv.x + hv.y + hv.z + hv.w;
        unsigned cum = lsum;
        #pragma unroll
        for (int off = 1; off < 64; off <<= 1){
            unsigned v = __shfl_down(cum, off);
            if (lane + off < 64) cum += v;
        }
        bool has = (cum >= (unsigned)need);
        unsigned long long bal = __ballot(has);
        int Ls = 63 - __clzll(bal);
        unsigned cA = __shfl(cum, Ls) - __shfl(lsum, Ls);
        unsigned h0 = __shfl(hv.x, Ls), h1 = __shfl(hv.y, Ls);
        unsigned h2 = __shfl(hv.z, Ls), h3 = __shfl(hv.w, Ls);
        int bin; unsigned above;
        if      (cA + h3 >= (unsigned)need)           { bin = 4*Ls + 3; above = cA; }
        else if (cA + h3 + h2 >= (unsigned)need)      { bin = 4*Ls + 2; above = cA + h3; }
        else if (cA + h3 + h2 + h1 >= (unsigned)need) { bin = 4*Ls + 1; above = cA + h3 + h2; }
        else                                          { bin = 4*Ls;     above = cA + h3 + h2 + h1; }
        need -= (int)above;
        prefix |= ((unsigned)bin) << sh;
        (void)h0;
        __syncthreads();
    }
    unsigned t = prefix;                 // exact key of the 20th largest
    unsigned mgt = 0u, meq = 0u;
    #pragma unroll
    for (int j = 0; j < 32; j++){
        mgt |= (u[j] > t)  ? (1u << j) : 0u;
        meq |= (u[j] == t) ? (1u << j) : 0u;
    }
    int cnt = __popc(mgt);
    int incl = cnt;
    #pragma unroll
    for (int off = 1; off < 64; off <<= 1){
        int v = __shfl_up(incl, off);
        if (lane >= off) incl += v;
    }
    int total_gt = __shfl(incl, 63);
    int slot = incl - cnt;
    unsigned mm = mgt;
    while (mm){
        int j = __ffs(mm) - 1;
        mm &= mm - 1u;
        hist[slot] = u[j];
        hist[32 + slot] = (unsigned)(j*64 + lane);
        slot++;
    }
    int fill = KK - total_gt;
    int base = total_gt;
    #pragma unroll
    for (int j = 0; j < 32; j++){
        unsigned long long bj = __ballot((meq >> j) & 1u);
        if (fill > 0 && bj){
            int cntj = __popcll(bj);
            int take = (cntj < fill) ? cntj : fill;
            unsigned long long below = bj & ((1ull << lane) - 1ull);
            int rank = __popcll(below);
            if (((bj >> lane) & 1ull) && rank < take){
                hist[base + rank] = t;
                hist[32 + base + rank] = (unsigned)(j*64 + lane);
            }
            base += take; fill -= take;
        }
    }
    __syncthreads();
    if (lane < KK){
        unsigned mu = hist[lane], mi = hist[32 + lane];
        int rank = 0;
        #pragma unroll
        for (int o = 0; o < KK; o++){
            unsigned ou = hist[o], oi = hist[32 + o];
            rank += (ou > mu || (ou == mu && oi < mi)) ? 1 : 0;
        }
        orow[rank] = (int)mi;
    }
}

// ---------------- K0: echo (B,C,N) -> (B,N,C) fp32 ----------------
__global__ void k_echo(const float* __restrict__ x, float* __restrict__ out0){
    int t = blockIdx.x * 256 + threadIdx.x;
    if (t >= BB*CC*NN) return;
    int b = t / (CC*NN); int r = t % (CC*NN); int c = r / NN; int n = r % NN;
    out0[(b*NN + n)*CC + c] = x[t];
}

// ---------------- K1: knn on 3-d coords ----------------
__global__ __launch_bounds__(256) void k_knn3(const float* __restrict__ x, int* __restrict__ idx){
    __shared__ float crd[NN*3];
    __shared__ __align__(16) unsigned shist[4*256];
    int b  = blockIdx.x / (NN/4);
    int rb = blockIdx.x % (NN/4);
    for (int c = 0; c < 3; c++)
        for (int p = threadIdx.x; p < NN; p += 256)
            crd[p*3 + c] = x[(b*CC + 6 + c)*NN + p];
    __syncthreads();
    int lane = threadIdx.x & 63;
    int wid  = threadIdx.x >> 6;
    int n = rb*4 + wid;
    float qx = crd[n*3], qy = crd[n*3+1], qz = crd[n*3+2];
    float sqn = qx*qx + qy*qy + qz*qz;
    unsigned u[32];
    #pragma unroll
    for (int j = 0; j < 32; j++){
        int m = j*64 + lane;
        float mx = crd[m*3], my = crd[m*3+1], mz = crd[m*3+2];
        float d = 2.f*(qx*mx + qy*my + qz*mz) - sqn - (mx*mx + my*my + mz*mz);
        u[j] = f2sort(d);
    }
    topk20(u, lane, shist + wid*256, idx + (b*NN + n)*KK);
}

// ---------------- P/Q stage 1 ----------------
__global__ __launch_bounds__(256) void k_pq9(const float* __restrict__ x, const float* __restrict__ w,
                                             float* __restrict__ P, float* __restrict__ Q){
    __shared__ __align__(16) float Xs[64*16];
    __shared__ __align__(16) float Wp[12*68];
    __shared__ __align__(16) float Wq[12*68];
    int row0 = blockIdx.x * 64;
    int b  = row0 >> 11;
    int n0 = row0 & (NN-1);
    int tx = threadIdx.x & 15, ty = threadIdx.x >> 4;
    for (int i = threadIdx.x; i < 64*12; i += 256){
        int r = i & 63, c = i >> 6;
        Xs[r*16 + c] = (c < 9) ? x[(b*CC + c)*NN + n0 + r] : 0.f;
    }
    for (int i = threadIdx.x; i < 64*12; i += 256){
        int c = i % 12, o = i / 12;
        float a = 0.f, dd = 0.f;
        if (c < 9){
            a  = w[o*18 + c];
            dd = w[o*18 + 9 + c] - a;
        }
        Wp[c*68 + o] = a;
        Wq[c*68 + o] = dd;
    }
    __syncthreads();
    float ap[4][4] = {{0.f}}, aq[4][4] = {{0.f}};
    for (int c0 = 0; c0 < 12; c0 += 4){
        float wp4[16], wq4[16];
        #pragma unroll
        for (int q = 0; q < 4; q++){
            *(float4*)&wp4[q*4] = *(const float4*)&Wp[(c0 + q)*68 + tx*4];
            *(float4*)&wq4[q*4] = *(const float4*)&Wq[(c0 + q)*68 + tx*4];
        }
        #pragma unroll
        for (int ii = 0; ii < 4; ii++){
            float4 x4 = *(const float4*)&Xs[(ty*4 + ii)*16 + c0];
            #pragma unroll
            for (int jj = 0; jj < 4; jj++){
                ap[ii][jj] += x4.x*wp4[jj] + x4.y*wp4[4+jj] + x4.z*wp4[8+jj] + x4.w*wp4[12+jj];
                aq[ii][jj] += x4.x*wq4[jj] + x4.y*wq4[4+jj] + x4.z*wq4[8+jj] + x4.w*wq4[12+jj];
            }
        }
    }
    #pragma unroll
    for (int ii = 0; ii < 4; ii++){
        int row = row0 + ty*4 + ii;
        store4(&P[row*64 + tx*4], ap[ii][0], ap[ii][1], ap[ii][2], ap[ii][3]);
        store4(&Q[row*64 + tx*4], aq[ii][0], aq[ii][1], aq[ii][2], aq[ii][3]);
    }
}

// ---------------- P/Q stages 2/3 ----------------
__global__ __launch_bounds__(256) void k_pq64(const float* __restrict__ X, const float* __restrict__ w,
                                              float* __restrict__ P, float* __restrict__ Q){
    __shared__ __align__(16) float Xs[64*68];
    __shared__ __align__(16) float Wp[64*68];
    __shared__ __align__(16) float Wq[64*68];
    int row0 = blockIdx.x * 64;
    int tx = threadIdx.x & 15, ty = threadIdx.x >> 4;
    for (int i = threadIdx.x; i < 64*64; i += 256){
        int c = i & 63, r = i >> 6;
        Xs[r*68 + c] = X[(row0 + r)*64 + c];
    }
    for (int i = threadIdx.x; i < 64*64; i += 256){
        int c = i & 63, o = i >> 6;
        float a  = w[o*128 + c];
        Wp[c*68 + o] = a;
        Wq[c*68 + o] = w[o*128 + 64 + c] - a;
    }
    __syncthreads();
    float ap[4][4] = {{0.f}}, aq[4][4] = {{0.f}};
    for (int c0 = 0; c0 < 64; c0 += 4){
        float wp4[16], wq4[16];
        #pragma unroll
        for (int q = 0; q < 4; q++){
            *(float4*)&wp4[q*4] = *(const float4*)&Wp[(c0 + q)*68 + tx*4];
            *(float4*)&wq4[q*4] = *(const float4*)&Wq[(c0 + q)*68 + tx*4];
        }
        #pragma unroll
        for (int ii = 0; ii < 4; ii++){
            float4 x4 = *(const float4*)&Xs[(ty*4 + ii)*68 + c0];
            #pragma unroll
            for (int jj = 0; jj < 4; jj++){
                ap[ii][jj] += x4.x*wp4[jj] + x4.y*wp4[4+jj] + x4.z*wp4[8+jj] + x4.w*wp4[12+jj];
                aq[ii][jj] += x4.x*wq4[jj] + x4.y*wq4[4+jj] + x4.z*wq4[8+jj] + x4.w*wq4[12+jj];
            }
        }
    }
    #pragma unroll
    for (int ii = 0; ii < 4; ii++){
        int row = row0 + ty*4 + ii;
        store4(&P[row*64 + tx*4], ap[ii][0], ap[ii][1], ap[ii][2], ap[ii][3]);
        store4(&Q[row*64 + tx*4], aq[ii][0], aq[ii][1], aq[ii][2], aq[ii][3]);
    }
}

// ---------------- PASS A: stats of h = P[j]+Q[n]; optional fused max-over-k ----------------
template<bool DOMAX>
__global__ __launch_bounds__(256) void k_hstats(const float* __restrict__ P, const float* __restrict__ Q,
                                                const int* __restrict__ nbr, float* __restrict__ Xraw,
                                                double* __restrict__ dsum, double* __restrict__ dssq){
    __shared__ float sbuf[16*64];
    __shared__ float qbuf[16*64];
    int row0 = blockIdx.x * 80;
    int tx = threadIdx.x & 15, ty = threadIdx.x >> 4;
    int ng = (row0 + ty*5) / 20;
    int b  = ng >> 11;
    float4 q4 = *(const float4*)&Q[ng*64 + tx*4];
    float s[4] = {0.f,0.f,0.f,0.f}, s2[4] = {0.f,0.f,0.f,0.f};
    float m[4] = {-INFINITY,-INFINITY,-INFINITY,-INFINITY};
    #pragma unroll
    for (int ii = 0; ii < 5; ii++){
        int e = row0 + ty*5 + ii;
        int j = nbr[e];
        float4 p4 = *(const float4*)&P[((b << 11) + j)*64 + tx*4];
        float h0 = p4.x + q4.x, h1 = p4.y + q4.y, h2 = p4.z + q4.z, h3 = p4.w + q4.w;
        s[0] += h0; s[1] += h1; s[2] += h2; s[3] += h3;
        s2[0] += h0*h0; s2[1] += h1*h1; s2[2] += h2*h2; s2[3] += h3*h3;
        if (DOMAX){
            m[0] = fmaxf(m[0], h0); m[1] = fmaxf(m[1], h1);
            m[2] = fmaxf(m[2], h2); m[3] = fmaxf(m[3], h3);
        }
    }
    #pragma unroll
    for (int jj = 0; jj < 4; jj++){
        sbuf[ty*64 + tx*4 + jj] = s[jj];
        qbuf[ty*64 + tx*4 + jj] = s2[jj];
    }
    if (DOMAX){
        #pragma unroll
        for (int off = 32; off >= 16; off >>= 1){
            #pragma unroll
            for (int jj = 0; jj < 4; jj++) m[jj] = fmaxf(m[jj], __shfl_xor(m[jj], off));
        }
        int lane = threadIdx.x & 63;
        if (lane < 16){
            int pi = ty >> 2;
            store4(&Xraw[(row0/20 + pi)*64 + tx*4], m[0], m[1], m[2], m[3]);
        }
    }
    __syncthreads();
    if (threadIdx.x < 64){
        double t = 0.0;
        #pragma unroll
        for (int k = 0; k < 16; k++) t += (double)sbuf[k*64 + threadIdx.x];
        atomicAdd(&dsum[threadIdx.x], t);
    } else if (threadIdx.x < 128){
        int c = threadIdx.x - 64;
        double t = 0.0;
        #pragma unroll
        for (int k = 0; k < 16; k++) t += (double)qbuf[k*64 + c];
        atomicAdd(&dssq[c], t);
    }
}

// ---------------- PASS B: edge GEMM, fused stats + max-over-k ----------------
__global__ __launch_bounds__(256) void k_edgegemm(const float* __restrict__ P, const float* __restrict__ Q,
                                                  const int* __restrict__ nbr,
                                                  const float* __restrict__ sc, const float* __restrict__ sh,
                                                  const float* __restrict__ w,
                                                  float* __restrict__ Xraw,
                                                  double* __restrict__ dsum, double* __restrict__ dssq){
    __shared__ __align__(16) float Fs[80*68];
    __shared__ __align__(16) float Ws[64*68];
    __shared__ float sbuf[16*64];
    __shared__ float qbuf[16*64];
    int row0 = blockIdx.x * 80;
    for (int i = threadIdx.x; i < 80*64; i += 256){
        int c = i & 63, r = i >> 6;
        int e  = row0 + r;
        int ng = e / 20;
        int b  = ng >> 11;
        int j  = nbr[e];
        float h = P[((b << 11) + j)*64 + c] + Q[ng*64 + c];
        Fs[r*68 + c] = lrelu(h*sc[c] + sh[c]);
    }
    for (int i = threadIdx.x; i < 64*64; i += 256){
        int c = i & 63, o = i >> 6;
        Ws[c*68 + o] = w[o*64 + c];
    }
    __syncthreads();
    int tx = threadIdx.x & 15, ty = threadIdx.x >> 4;
    float acc[5][4] = {{0.f}};
    for (int c0 = 0; c0 < 64; c0 += 4){
        float bb4[16];
        #pragma unroll
        for (int q = 0; q < 4; q++)
            *(float4*)&bb4[q*4] = *(const float4*)&Ws[(c0 + q)*68 + tx*4];
        #pragma unroll
        for (int ii = 0; ii < 5; ii++){
            float4 a4 = *(const float4*)&Fs[(ty*5 + ii)*68 + c0];
            #pragma unroll
            for (int jj = 0; jj < 4; jj++)
                acc[ii][jj] += a4.x*bb4[jj] + a4.y*bb4[4+jj] + a4.z*bb4[8+jj] + a4.w*bb4[12+jj];
        }
    }
    float m[4];
    #pragma unroll
    for (int jj = 0; jj < 4; jj++){
        sbuf[ty*64 + tx*4 + jj] = acc[0][jj] + acc[1][jj] + acc[2][jj] + acc[3][jj] + acc[4][jj];
        qbuf[ty*64 + tx*4 + jj] = acc[0][jj]*acc[0][jj] + acc[1][jj]*acc[1][jj] + acc[2][jj]*acc[2][jj]
                                + acc[3][jj]*acc[3][jj] + acc[4][jj]*acc[4][jj];
        m[jj] = fmaxf(fmaxf(fmaxf(acc[0][jj], acc[1][jj]), fmaxf(acc[2][jj], acc[3][jj])), acc[4][jj]);
    }
    #pragma unroll
    for (int off = 32; off >= 16; off >>= 1){
        #pragma unroll
        for (int jj = 0; jj < 4; jj++) m[jj] = fmaxf(m[jj], __shfl_xor(m[jj], off));
    }
    int lane = threadIdx.x & 63;
    if (lane < 16){
        int pi = ty >> 2;
        store4(&Xraw[(row0/20 + pi)*64 + tx*4], m[0], m[1], m[2], m[3]);
    }
    __syncthreads();
    if (threadIdx.x < 64){
        double t = 0.0;
        #pragma unroll
        for (int k = 0; k < 16; k++) t += (double)sbuf[k*64 + threadIdx.x];
        atomicAdd(&dsum[threadIdx.x], t);
    } else if (threadIdx.x < 128){
        int c = threadIdx.x - 64;
        double t = 0.0;
        #pragma unroll
        for (int k = 0; k < 16; k++) t += (double)qbuf[k*64 + c];
        atomicAdd(&dssq[c], t);
    }
}

// ---------------- BN finalize ----------------
__global__ void k_finalize(const double* __restrict__ dsum, const double* __restrict__ dssq,
                           const float* __restrict__ g, const float* __restrict__ b,
                           float* __restrict__ scale, float* __restrict__ shift,
                           int ch, double inv_cnt){
    int c = blockIdx.x*256 + threadIdx.x;
    if (c >= ch) return;
    double m = dsum[c] * inv_cnt;
    double v = dssq[c] * inv_cnt - m*m;
    if (v < 0.0) v = 0.0;
    float rs = (float)(1.0 / sqrt(v + 1e-5));
    float sc = g[c] * rs;
    scale[c] = sc;
    shift[c] = b[c] - (float)m*sc;
}

// ---------------- in-place bn+lrelu on (16384 x 64) ----------------
__global__ void k_bnact(float* __restrict__ X, const float* __restrict__ sc, const float* __restrict__ sh){
    int t = blockIdx.x*256 + threadIdx.x;
    int c = t & 63;
    X[t] = lrelu(X[t]*sc[c] + sh[c]);
}

// ---------------- in-place bn8+lrelu on out1 (B,256,N) ----------------
__global__ void k_bnact8(float* __restrict__ O, const float* __restrict__ sc, const float* __restrict__ sh){
    int t = blockIdx.x*256 + threadIdx.x;
    int oc = (t >> 11) & 255;
    O[t] = lrelu(O[t]*sc[oc] + sh[oc]);
}

// ---------------- per-row squared norm ----------------
__global__ void k_sqnorm(const float* __restrict__ X, float* __restrict__ sqn){
    int row  = blockIdx.x*4 + (threadIdx.x >> 6);
    int lane = threadIdx.x & 63;
    float v = X[row*64 + lane];
    float s = v*v;
    #pragma unroll
    for (int off = 32; off >= 1; off >>= 1) s += __shfl_xor(s, off);
    if (lane == 0) sqn[row] = s;
}

// ---------------- Gram, up to 2 batches per dispatch: 128x128 tile, 8x8/thread ----------------
__global__ __launch_bounds__(256) void k_gram2(const float* __restrict__ X, float* G0, float* G1, int b0){
    __shared__ __align__(16) float As[32*132];
    __shared__ __align__(16) float Bs[32*132];
    int sub = blockIdx.x >> 8;
    int t   = blockIdx.x & 255;
    const float* Xb = X + (size_t)(b0 + sub)*NN*64;
    float* gram = sub ? G1 : G0;
    int tr = t >> 4, tc = t & 15;
    int tx = threadIdx.x & 15, ty = threadIdx.x >> 4;
    float acc[8][8];
    #pragma unroll
    for (int i = 0; i < 8; i++)
        #pragma unroll
        for (int j = 0; j < 8; j++) acc[i][j] = 0.f;
    for (int kc0 = 0; kc0 < 64; kc0 += 32){
        __syncthreads();
        for (int i = threadIdx.x; i < 128*32; i += 256){
            int k = i & 31, r = i >> 5;
            As[k*132 + r] = Xb[(tr*128 + r)*64 + kc0 + k];
            Bs[k*132 + r] = Xb[(tc*128 + r)*64 + kc0 + k];
        }
        __syncthreads();
        for (int k = 0; k < 32; k++){
            float4 a0 = *(const float4*)&As[k*132 + ty*8];
            float4 a1 = *(const float4*)&As[k*132 + ty*8 + 4];
            float4 b0v = *(const float4*)&Bs[k*132 + tx*8];
            float4 b1v = *(const float4*)&Bs[k*132 + tx*8 + 4];
            float av[8] = {a0.x,a0.y,a0.z,a0.w,a1.x,a1.y,a1.z,a1.w};
            float bv[8] = {b0v.x,b0v.y,b0v.z,b0v.w,b1v.x,b1v.y,b1v.z,b1v.w};
            #pragma unroll
            for (int i = 0; i < 8; i++)
                #pragma unroll
                for (int j = 0; j < 8; j++) acc[i][j] += av[i]*bv[j];
        }
    }
    #pragma unroll
    for (int i = 0; i < 8; i++){
        int row = tr*128 + ty*8 + i;
        *(float4*)&gram[row*NN + tc*128 + tx*8]     = make_float4(acc[i][0],acc[i][1],acc[i][2],acc[i][3]);
        *(float4*)&gram[row*NN + tc*128 + tx*8 + 4] = make_float4(acc[i][4],acc[i][5],acc[i][6],acc[i][7]);
    }
}

// ---------------- top-20 from gram rows, up to 2 batches per dispatch ----------------
__global__ __launch_bounds__(256) void k_sel2(const float* G0, const float* G1,
                                              const float* __restrict__ sqn, int* __restrict__ idx){
    __shared__ __align__(16) unsigned shist[4*256];
    int sub = blockIdx.x >> 9;
    int rb  = blockIdx.x & 511;
    const float* gram = sub ? G1 : G0;
    const float* sq   = sqn + sub*NN;
    int lane = threadIdx.x & 63;
    int wid  = threadIdx.x >> 6;
    int n = rb*4 + wid;
    const float* grow = gram + (size_t)n*NN;
    float sn = sq[n];
    unsigned u[32];
    #pragma unroll
    for (int j = 0; j < 32; j++){
        int m = j*64 + lane;
        u[j] = f2sort(2.f*grow[m] - sn - sq[m]);
    }
    topk20(u, lane, shist + wid*256, idx + (sub*NN + n)*KK);
}

// ---------------- C7 precompute: C7[b][oc] = sum_{c<1024} gmax[b,c] * w7[oc,c] ----------------
__global__ __launch_bounds__(256) void k_c7(const float* __restrict__ gmax, const float* __restrict__ w7,
                                            float* __restrict__ C7){
    __shared__ float red[4*8];
    int oc = blockIdx.x;
    int tid = threadIdx.x, lane = tid & 63, wid = tid >> 6;
    float a[8];
    #pragma unroll
    for (int b = 0; b < 8; b++) a[b] = 0.f;
    for (int k = tid; k < 1024; k += 256){
        float wv = w7[oc*1216 + k];
        #pragma unroll
        for (int b = 0; b < 8; b++) a[b] += gmax[b*1024 + k] * wv;
    }
    #pragma unroll
    for (int b = 0; b < 8; b++){
        #pragma unroll
        for (int off = 32; off >= 1; off >>= 1) a[b] += __shfl_xor(a[b], off);
        if (lane == 0) red[wid*8 + b] = a[b];
    }
    __syncthreads();
    if (tid < 8){
        float s = red[tid] + red[8 + tid] + red[16 + tid] + red[24 + tid];
        C7[tid*512 + oc] = s;
    }
}

// ---------------- unified head GEMM: 128x128 tile, 8x8/thread, stats; optional maxN/bias/store ----------------
template<int MODE, bool MAXN, int STMODE, typename TST, typename TH7>
__global__ __launch_bounds__(256) void k_head(
    const float* __restrict__ X1, const float* __restrict__ X2, const float* __restrict__ X3,
    const TH7*  __restrict__ H7, const float* __restrict__ C7,
    const float* __restrict__ sc_in, const float* __restrict__ sh_in,
    const float* __restrict__ w,
    TST* __restrict__ HST, float* __restrict__ out1t, float* __restrict__ part,
    double* __restrict__ dsum, double* __restrict__ dssq)
{
    constexpr int CIN  = (MODE == 4) ? 512 : 192;
    constexpr int WST  = (MODE == 2) ? 192 : (MODE == 3 ? 1216 : 512);
    constexpr int WOFF = (MODE == 3) ? 1024 : 0;
    constexpr int COUT = (MODE == 2) ? 1024 : (MODE == 3 ? 512 : 256);
    __shared__ __align__(16) float As[32*132];
    __shared__ __align__(16) float Bs[32*132];
    int tid = threadIdx.x;
    int rt = blockIdx.x & 127;
    int ct = blockIdx.x >> 7;
    int row0 = rt * 128;
    int col0 = ct * 128;
    int b = row0 >> 11;
    int tx = tid & 15, ty = tid >> 4;
    float acc[8][8];
    #pragma unroll
    for (int i = 0; i < 8; i++)
        #pragma unroll
        for (int j = 0; j < 8; j++) acc[i][j] = 0.f;
    for (int s = 0; s < CIN/32; s++){
        int cg0 = s*32;
        float scv = 0.f, shv = 0.f;
        if (MODE == 4){ scv = sc_in[cg0 + (tid & 31)]; shv = sh_in[cg0 + (tid & 31)]; }
        __syncthreads();
        for (int i = tid; i < 128*32; i += 256){
            int k = i & 31, r = i >> 5;
            float v;
            if (MODE == 4){
                v = lrelu((float)H7[(row0 + r)*512 + cg0 + k]*scv + shv);
            } else {
                const float* S = (cg0 < 64) ? X1 : (cg0 < 128 ? X2 : X3);
                int co = cg0 & 63;
                v = S[(row0 + r)*64 + co + k];
            }
            As[k*132 + r] = v;
        }
        for (int i = tid; i < 128*32; i += 256){
            int k = i & 31, n = i >> 5;
            Bs[k*132 + n] = w[(col0 + n)*WST + WOFF + cg0 + k];
        }
        __syncthreads();
        for (int k = 0; k < 32; k++){
            float4 a0 = *(const float4*)&As[k*132 + ty*8];
            float4 a1 = *(const float4*)&As[k*132 + ty*8 + 4];
            float4 b0 = *(const float4*)&Bs[k*132 + tx*8];
            float4 b1 = *(const float4*)&Bs[k*132 + tx*8 + 4];
            float av[8] = {a0.x,a0.y,a0.z,a0.w,a1.x,a1.y,a1.z,a1.w};
            float bv[8] = {b0.x,b0.y,b0.z,b0.w,b1.x,b1.y,b1.z,b1.w};
            #pragma unroll
            for (int i = 0; i < 8; i++)
                #pragma unroll
                for (int j = 0; j < 8; j++) acc[i][j] += av[i]*bv[j];
        }
    }
    if (MODE == 3){
        #pragma unroll
        for (int j = 0; j < 8; j++){
            float c7 = C7[b*512 + col0 + tx*8 + j];
            #pragma unroll
            for (int i = 0; i < 8; i++) acc[i][j] += c7;
        }
    }
    if (STMODE == 1){
        #pragma unroll
        for (int i = 0; i < 8; i++){
            int row = row0 + ty*8 + i;
            store4(&HST[row*COUT + col0 + tx*8],     acc[i][0], acc[i][1], acc[i][2], acc[i][3]);
            store4(&HST[row*COUT + col0 + tx*8 + 4], acc[i][4], acc[i][5], acc[i][6], acc[i][7]);
        }
    } else if (STMODE == 2){
        int n0 = (row0 & (NN-1)) + ty*8;
        #pragma unroll
        for (int j = 0; j < 8; j++){
            float* o = out1t + b*256*NN + (col0 + tx*8 + j)*NN + n0;
            *(float4*)o       = make_float4(acc[0][j], acc[1][j], acc[2][j], acc[3][j]);
            *(float4*)(o + 4) = make_float4(acc[4][j], acc[5][j], acc[6][j], acc[7][j]);
        }
    }
    __syncthreads();
    float* sbuf = As;
    float* qbuf = As + 2048;
    float* mbuf = Bs;
    #pragma unroll
    for (int j = 0; j < 8; j++){
        float sv = 0.f, qv = 0.f, mv = -INFINITY;
        #pragma unroll
        for (int i = 0; i < 8; i++){
            sv += acc[i][j];
            qv += acc[i][j]*acc[i][j];
            if (MAXN) mv = fmaxf(mv, acc[i][j]);
        }
        sbuf[ty*128 + tx*8 + j] = sv;
        qbuf[ty*128 + tx*8 + j] = qv;
        if (MAXN) mbuf[ty*128 + tx*8 + j] = mv;
    }
    __syncthreads();
    if (tid < 128){
        double t = 0.0;
        #pragma unroll
        for (int k = 0; k < 16; k++) t += (double)sbuf[k*128 + tid];
        atomicAdd(&dsum[col0 + tid], t);
        if (MAXN){
            float mm = -INFINITY;
            #pragma unroll
            for (int k = 0; k < 16; k++) mm = fmaxf(mm, mbuf[k*128 + tid]);
            part[rt*1024 + col0 + tid] = mm;
        }
    } else {
        int c = tid - 128;
        double t = 0.0;
        #pragma unroll
        for (int k = 0; k < 16; k++) t += (double)qbuf[k*128 + c];
        atomicAdd(&dssq[col0 + c], t);
    }
}

// ---------------- reduce partial maxes, apply bn6+lrelu ----------------
__global__ void k_gmax_fin(const float* __restrict__ part, const float* __restrict__ sc,
                           const float* __restrict__ sh, float* __restrict__ gmax){
    int t = blockIdx.x*256 + threadIdx.x;
    int b = t >> 10, c = t & 1023;
    float m = -INFINITY;
    #pragma unroll
    for (int k = 0; k < 16; k++) m = fmaxf(m, part[(b*16 + k)*1024 + c]);
    gmax[t] = lrelu(m*sc[c] + sh[c]);
}

// ---------------- tier C: BN8+lrelu + transpose from stored H8 bf16 ----------------
__global__ __launch_bounds__(256) void k_final_b(const bf16* __restrict__ H8,
                                                 const float* __restrict__ scale,
                                                 const float* __restrict__ shift,
                                                 float* __restrict__ out1){
    __shared__ float tile[64*65];
    int bi = blockIdx.x;
    int b  = bi / 128;
    int r  = bi % 128;
    int nt = r >> 2, ot = r & 3;
    for (int i = threadIdx.x; i < 64*64; i += 256){
        int o = i & 63, nl = i >> 6;
        float v = (float)H8[((b*NN) + nt*64 + nl)*256 + ot*64 + o];
        int oc = ot*64 + o;
        tile[o*65 + nl] = lrelu(v*scale[oc] + shift[oc]);
    }
    __syncthreads();
    for (int i = threadIdx.x; i < 64*64; i += 256){
        int nl = i & 63, o = i >> 6;
        out1[b*256*NN + (ot*64 + o)*NN + nt*64 + nl] = tile[o*65 + nl];
    }
}

// ---------------- host launcher ----------------
extern "C" void kernel_launch(void* const* d_in, const int* in_sizes, int n_in,
                              void* d_out, int out_size, void* d_ws, size_t ws_size,
                              hipStream_t stream){
    const float* x = (const float*)d_in[0];
    const float *w[8], *g[8], *bb[8];
    for (int i = 0; i < 8; i++){
        w[i]  = (const float*)d_in[1 + i*3];
        g[i]  = (const float*)d_in[2 + i*3];
        bb[i] = (const float*)d_in[3 + i*3];
    }
    float* ws  = (float*)d_ws;
    float* X1  = ws + OFF_X1;
    float* X2  = ws + OFF_X2;
    float* X3  = ws + OFF_X3;
    float* SQN = ws + OFF_SQN;
    float* GMAX= ws + OFF_GMAX;
    float* PART= ws + OFF_PART;
    float* C7  = ws + OFF_PART + 131072;
    double* DS = (double*)(ws + OFF_STATS);
    float*  FS = ws + OFF_STATS + 8448;
    int*   IDX = (int*)(ws + OFF_IDX);

    float* out0 = (float*)d_out;
    float* out1 = out0 + BB*NN*CC;
    float* P    = out1;
    float* Q    = out1 + 1048576;
    float* GRAM0= out1;
    float* GRAM1= ws + BASE_END;
    bool dualGram = ws_size >= (size_t)(BASE_END + 4194304)*4;

    const int chs[8]   = {64,64,64,64,64,1024,512,256};
    const int base[8]  = {0,128,256,384,512,640,2688,3712};
    double *SUMp[8], *SSQp[8];
    float  *SCp[8],  *SHp[8];
    for (int L = 0; L < 8; L++){
        SUMp[L] = DS + base[L];
        SSQp[L] = DS + base[L] + chs[L];
        SCp[L]  = FS + base[L];
        SHp[L]  = FS + base[L] + chs[L];
    }
    const double invE = 1.0 / (double)(BB*NN*KK);
    const double invP = 1.0 / (double)(BB*NN);

    hipMemsetAsync(DS, 0, 4224*sizeof(double), stream);
    k_echo<<<576,256,0,stream>>>(x, out0);

    // ---- stage 1 ----
    k_knn3<<<BB*NN/4,256,0,stream>>>(x, IDX);
    k_pq9<<<256,256,0,stream>>>(x, w[0], P, Q);
    k_hstats<false><<<4096,256,0,stream>>>(P, Q, IDX, nullptr, SUMp[0], SSQp[0]);
    k_finalize<<<1,256,0,stream>>>(SUMp[0],SSQp[0],g[0],bb[0],SCp[0],SHp[0],64,invE);
    k_edgegemm<<<4096,256,0,stream>>>(P, Q, IDX, SCp[0], SHp[0], w[1], X1, SUMp[1], SSQp[1]);
    k_finalize<<<1,256,0,stream>>>(SUMp[1],SSQp[1],g[1],bb[1],SCp[1],SHp[1],64,invE);
    k_bnact<<<4096,256,0,stream>>>(X1, SCp[1], SHp[1]);

    // ---- stage 2 & 3 knn + edge ----
    for (int stage = 0; stage < 2; stage++){
        float* Xs = (stage == 0) ? X1 : X2;
        k_sqnorm<<<4096,256,0,stream>>>(Xs, SQN);
        if (dualGram){
            for (int pr = 0; pr < 4; pr++){
                k_gram2<<<512,256,0,stream>>>(Xs, GRAM0, GRAM1, pr*2);
                k_sel2<<<1024,256,0,stream>>>(GRAM0, GRAM1, SQN + pr*2*NN, IDX + pr*2*NN*KK);
            }
        } else {
            for (int b = 0; b < BB; b++){
                k_gram2<<<256,256,0,stream>>>(Xs, GRAM0, GRAM0, b);
                k_sel2<<<512,256,0,stream>>>(GRAM0, GRAM0, SQN + b*NN, IDX + b*NN*KK);
            }
        }
        if (stage == 0){
            k_pq64<<<256,256,0,stream>>>(X1, w[2], P, Q);
            k_hstats<false><<<4096,256,0,stream>>>(P, Q, IDX, nullptr, SUMp[2], SSQp[2]);
            k_finalize<<<1,256,0,stream>>>(SUMp[2],SSQp[2],g[2],bb[2],SCp[2],SHp[2],64,invE);
            k_edgegemm<<<4096,256,0,stream>>>(P, Q, IDX, SCp[2], SHp[2], w[3], X2, SUMp[3], SSQp[3]);
            k_finalize<<<1,256,0,stream>>>(SUMp[3],SSQp[3],g[3],bb[3],SCp[3],SHp[3],64,invE);
            k_bnact<<<4096,256,0,stream>>>(X2, SCp[3], SHp[3]);
        } else {
            k_pq64<<<256,256,0,stream>>>(X2, w[4], P, Q);
            k_hstats<true><<<4096,256,0,stream>>>(P, Q, IDX, X3, SUMp[4], SSQp[4]);
            k_finalize<<<1,256,0,stream>>>(SUMp[4],SSQp[4],g[4],bb[4],SCp[4],SHp[4],64,invE);
            k_bnact<<<4096,256,0,stream>>>(X3, SCp[4], SHp[4]);
        }
    }

    // ---- layer 6 + global max ----
    k_head<2,true,0,float,float><<<1024,256,0,stream>>>(
        X1,X2,X3,(const float*)nullptr,nullptr,nullptr,nullptr,w[5],
        (float*)nullptr,nullptr,PART,SUMp[5],SSQp[5]);
    k_finalize<<<4,256,0,stream>>>(SUMp[5],SSQp[5],g[5],bb[5],SCp[5],SHp[5],1024,invP);
    k_gmax_fin<<<32,256,0,stream>>>(PART, SCp[5], SHp[5], GMAX);
    k_c7<<<512,256,0,stream>>>(GMAX, w[6], C7);

    // ---- layers 7/8, tiered by ws_size ----
    if (ws_size >= (size_t)12161536*4){
        float* H7f = ws + BASE_END;
        k_head<3,false,1,float,float><<<512,256,0,stream>>>(
            X1,X2,X3,(const float*)nullptr,C7,nullptr,nullptr,w[6],
            H7f,nullptr,nullptr,SUMp[6],SSQp[6]);
        k_finalize<<<2,256,0,stream>>>(SUMp[6],SSQp[6],g[6],bb[6],SCp[6],SHp[6],512,invP);
        k_head<4,false,2,float,float><<<256,256,0,stream>>>(
            nullptr,nullptr,nullptr,H7f,nullptr,SCp[6],SHp[6],w[7],
            (float*)nullptr,out1,nullptr,SUMp[7],SSQp[7]);
        k_finalize<<<1,256,0,stream>>>(SUMp[7],SSQp[7],g[7],bb[7],SCp[7],SHp[7],256,invP);
        k_bnact8<<<16384,256,0,stream>>>(out1, SCp[7], SHp[7]);
    } else if (ws_size >= (size_t)7967232*4){
        bf16* H7b = (bf16*)(ws + BASE_END);
        k_head<3,false,1,bf16,float><<<512,256,0,stream>>>(
            X1,X2,X3,(const float*)nullptr,C7,nullptr,nullptr,w[6],
            H7b,nullptr,nullptr,SUMp[6],SSQp[6]);
        k_finalize<<<2,256,0,stream>>>(SUMp[6],SSQp[6],g[6],bb[6],SCp[6],SHp[6],512,invP);
        k_head<4,false,2,float,bf16><<<256,256,0,stream>>>(
            nullptr,nullptr,nullptr,H7b,nullptr,SCp[6],SHp[6],w[7],
            (float*)nullptr,out1,nullptr,SUMp[7],SSQp[7]);
        k_finalize<<<1,256,0,stream>>>(SUMp[7],SSQp[7],g[7],bb[7],SCp[7],SHp[7],256,invP);
        k_bnact8<<<16384,256,0,stream>>>(out1, SCp[7], SHp[7]);
    } else {
        bf16* H7b = (bf16*)out1;
        bf16* H8b = (bf16*)(ws + OFF_X1);
        k_head<3,false,1,bf16,float><<<512,256,0,stream>>>(
            X1,X2,X3,(const float*)nullptr,C7,nullptr,nullptr,w[6],
            H7b,nullptr,nullptr,SUMp[6],SSQp[6]);
        k_finalize<<<2,256,0,stream>>>(SUMp[6],SSQp[6],g[6],bb[6],SCp[6],SHp[6],512,invP);
        k_head<4,false,1,bf16,bf16><<<256,256,0,stream>>>(
            nullptr,nullptr,nullptr,H7b,nullptr,SCp[6],SHp[6],w[7],
            H8b,nullptr,nullptr,SUMp[7],SSQp[7]);
        k_finalize<<<1,256,0,stream>>>(SUMp[7],SSQp[7],g[7],bb[7],SCp[7],SHp[7],256,invP);
        k_final_b<<<1024,256,0,stream>>>(H8b, SCp[7], SHp[7], out1);
    }
}

// Round 9
// 1196.640 us; speedup vs baseline: 1.8071x; 1.2545x over previous
//
#include <hip/hip_runtime.h>
#include <hip/hip_bf16.h>

typedef __hip_bfloat16 bf16;

#define BB 8
#define NN 2048
#define CC 9
#define KK 20

// ---------------- ws layout (float elements) ----------------
static constexpr int OFF_X1   = 0;               // 1048576 (16384x64 fp32)
static constexpr int OFF_X2   = 1048576;         // 1048576
static constexpr int OFF_X3   = 2097152;         // 1048576
static constexpr int OFF_SQN  = 3145728;         // 16384
static constexpr int OFF_GMAX = 3162112;         // 8192
static constexpr int OFF_PART = 3170304;         // 262144 (uses 131072; C7 at +131072)
static constexpr int OFF_STATS= 3432448;         // 12800 (4224 doubles + 4224 floats)
static constexpr int OFF_IDX  = 3445248;         // 327680 (int32)
static constexpr int BASE_END = 3772928;         // 15.1 MB
// BASE_END region (lifetimes disjoint): GRAM1 fp32 16MB (knn stages) | H7 (layer 7+)
// tier A: H7 fp32 (16384x512) -> 48.6 MB ; tier B: H7 bf16 -> 31.9 MB ; tier C: H7 bf16 in d_out
// d_out scratch (out1 region): P|Q, GRAM0, (tier C) H7-bf16; finally raw-h8/out1

__device__ __forceinline__ float lrelu(float x){ return x >= 0.f ? x : 0.2f * x; }

__device__ __forceinline__ void store4(float* p, float a, float b, float c, float d){
    *(float4*)p = make_float4(a,b,c,d);
}
__device__ __forceinline__ void store4(bf16* p, float a, float b, float c, float d){
    union { bf16 h[4]; uint2 u; } pk;
    pk.h[0] = (bf16)a; pk.h[1] = (bf16)b; pk.h[2] = (bf16)c; pk.h[3] = (bf16)d;
    *(uint2*)p = pk.u;
}

// float -> order-preserving uint32
__device__ __forceinline__ unsigned f2sort(float f){
    unsigned b = __float_as_uint(f);
    return b ^ (unsigned)(((int)b >> 31) | (int)0x80000000);
}

// exact fallback: 20x argmax-extract (desc value, asc index) — rare path
__device__ __forceinline__ void fallback_extract(unsigned (&u)[32], int lane, int* __restrict__ orow){
    for (int it = 0; it < KK; it++){
        unsigned bv = u[0]; int bj = 0;
        #pragma unroll
        for (int j = 1; j < 32; j++) if (u[j] > bv){ bv = u[j]; bj = j; }
        int bm = bj*64 + lane;
        #pragma unroll
        for (int off = 32; off >= 1; off >>= 1){
            unsigned ov = __shfl_xor(bv, off);
            int om = __shfl_xor(bm, off);
            if (ov > bv || (ov == bv && om < bm)){ bv = ov; bm = om; }
        }
        if (lane == 0) orow[it] = bm;
        if ((bm & 63) == lane) u[bm >> 6] = 0u;
    }
}

// ---------------- exact top-20 (largest) of 2048 candidates, one wave ----------------
// u[32]: lane's candidates; global index of u[j] = j*64 + lane.
// sval/sidx: wave-private 64-entry LDS arrays. orow: 20 ints out.
// Emits orow in (descending value, ascending index) order.
__device__ __forceinline__ void topk20(unsigned (&u)[32], int lane,
                                       unsigned* sval, unsigned* sidx, int* __restrict__ orow){
    // 1) lower bound t0 = 20th largest of the 64 lane-maxima (bitonic sort of ~max ascending)
    unsigned mx = 0u;
    #pragma unroll
    for (int j = 0; j < 32; j++) mx = (u[j] > mx) ? u[j] : mx;
    unsigned v = ~mx;
    #pragma unroll
    for (int k = 2; k <= 64; k <<= 1){
        #pragma unroll
        for (int j = k >> 1; j > 0; j >>= 1){
            unsigned o = __shfl_xor(v, j);
            bool keepMin = ((lane & k) == 0) == ((lane & j) == 0);
            bool less = (o < v);
            v = (keepMin == less) ? o : v;
        }
    }
    unsigned t0 = ~__shfl(v, 19);
    // 2) filter candidates >= t0 (guaranteed to contain the true top-20, and >=20 survivors)
    unsigned mask = 0u;
    #pragma unroll
    for (int j = 0; j < 32; j++) if (u[j] >= t0) mask |= (1u << j);
    int cnt = __popc(mask);
    int incl = cnt;
    #pragma unroll
    for (int off = 1; off < 64; off <<= 1){
        int t = __shfl_up(incl, off);
        if (lane >= off) incl += t;
    }
    int total = __shfl(incl, 63);
    if (total <= 64){
        // 3) compact survivors to LDS, one bitonic sort of composite (~key, idx) ascending
        int slot = incl - cnt;
        unsigned mm = mask;
        while (mm){
            int j = __ffs(mm) - 1;
            mm &= mm - 1u;
            sval[slot] = u[j];
            sidx[slot] = (unsigned)(j*64 + lane);
            slot++;
        }
        __threadfence_block();
        unsigned long long c = ~0ULL;
        if (lane < total)
            c = (((unsigned long long)(~sval[lane])) << 32) | (unsigned long long)sidx[lane];
        #pragma unroll
        for (int k = 2; k <= 64; k <<= 1){
            #pragma unroll
            for (int j = k >> 1; j > 0; j >>= 1){
                unsigned long long o = __shfl_xor(c, j);
                bool keepMin = ((lane & k) == 0) == ((lane & j) == 0);
                bool less = (o < c);
                c = (keepMin == less) ? o : c;
            }
        }
        if (lane < KK) orow[lane] = (int)(c & 0xffffffffULL);
    } else {
        fallback_extract(u, lane, orow);
    }
}

// ---------------- K0: echo (B,C,N) -> (B,N,C) fp32 ----------------
__global__ void k_echo(const float* __restrict__ x, float* __restrict__ out0){
    int t = blockIdx.x * 256 + threadIdx.x;
    if (t >= BB*CC*NN) return;
    int b = t / (CC*NN); int r = t % (CC*NN); int c = r / NN; int n = r % NN;
    out0[(b*NN + n)*CC + c] = x[t];
}

// ---------------- K1: knn on 3-d coords ----------------
__global__ __launch_bounds__(256) void k_knn3(const float* __restrict__ x, int* __restrict__ idx){
    __shared__ float crd[NN*3];
    __shared__ unsigned sval[4*64];
    __shared__ unsigned sidx[4*64];
    int b  = blockIdx.x / (NN/4);
    int rb = blockIdx.x % (NN/4);
    for (int c = 0; c < 3; c++)
        for (int p = threadIdx.x; p < NN; p += 256)
            crd[p*3 + c] = x[(b*CC + 6 + c)*NN + p];
    __syncthreads();
    int lane = threadIdx.x & 63;
    int wid  = threadIdx.x >> 6;
    int n = rb*4 + wid;
    float qx = crd[n*3], qy = crd[n*3+1], qz = crd[n*3+2];
    float sqn = qx*qx + qy*qy + qz*qz;
    unsigned u[32];
    #pragma unroll
    for (int j = 0; j < 32; j++){
        int m = j*64 + lane;
        float mx = crd[m*3], my = crd[m*3+1], mz = crd[m*3+2];
        float d = 2.f*(qx*mx + qy*my + qz*mz) - sqn - (mx*mx + my*my + mz*mz);
        u[j] = f2sort(d);
    }
    topk20(u, lane, sval + wid*64, sidx + wid*64, idx + (b*NN + n)*KK);
}

// ---------------- P/Q stage 1 ----------------
__global__ __launch_bounds__(256) void k_pq9(const float* __restrict__ x, const float* __restrict__ w,
                                             float* __restrict__ P, float* __restrict__ Q){
    __shared__ __align__(16) float Xs[64*16];
    __shared__ __align__(16) float Wp[12*68];
    __shared__ __align__(16) float Wq[12*68];
    int row0 = blockIdx.x * 64;
    int b  = row0 >> 11;
    int n0 = row0 & (NN-1);
    int tx = threadIdx.x & 15, ty = threadIdx.x >> 4;
    for (int i = threadIdx.x; i < 64*12; i += 256){
        int r = i & 63, c = i >> 6;
        Xs[r*16 + c] = (c < 9) ? x[(b*CC + c)*NN + n0 + r] : 0.f;
    }
    for (int i = threadIdx.x; i < 64*12; i += 256){
        int c = i % 12, o = i / 12;
        float a = 0.f, dd = 0.f;
        if (c < 9){
            a  = w[o*18 + c];
            dd = w[o*18 + 9 + c] - a;
        }
        Wp[c*68 + o] = a;
        Wq[c*68 + o] = dd;
    }
    __syncthreads();
    float ap[4][4] = {{0.f}}, aq[4][4] = {{0.f}};
    for (int c0 = 0; c0 < 12; c0 += 4){
        float wp4[16], wq4[16];
        #pragma unroll
        for (int q = 0; q < 4; q++){
            *(float4*)&wp4[q*4] = *(const float4*)&Wp[(c0 + q)*68 + tx*4];
            *(float4*)&wq4[q*4] = *(const float4*)&Wq[(c0 + q)*68 + tx*4];
        }
        #pragma unroll
        for (int ii = 0; ii < 4; ii++){
            float4 x4 = *(const float4*)&Xs[(ty*4 + ii)*16 + c0];
            #pragma unroll
            for (int jj = 0; jj < 4; jj++){
                ap[ii][jj] += x4.x*wp4[jj] + x4.y*wp4[4+jj] + x4.z*wp4[8+jj] + x4.w*wp4[12+jj];
                aq[ii][jj] += x4.x*wq4[jj] + x4.y*wq4[4+jj] + x4.z*wq4[8+jj] + x4.w*wq4[12+jj];
            }
        }
    }
    #pragma unroll
    for (int ii = 0; ii < 4; ii++){
        int row = row0 + ty*4 + ii;
        store4(&P[row*64 + tx*4], ap[ii][0], ap[ii][1], ap[ii][2], ap[ii][3]);
        store4(&Q[row*64 + tx*4], aq[ii][0], aq[ii][1], aq[ii][2], aq[ii][3]);
    }
}

// ---------------- P/Q stages 2/3 ----------------
__global__ __launch_bounds__(256) void k_pq64(const float* __restrict__ X, const float* __restrict__ w,
                                              float* __restrict__ P, float* __restrict__ Q){
    __shared__ __align__(16) float Xs[64*68];
    __shared__ __align__(16) float Wp[64*68];
    __shared__ __align__(16) float Wq[64*68];
    int row0 = blockIdx.x * 64;
    int tx = threadIdx.x & 15, ty = threadIdx.x >> 4;
    for (int i = threadIdx.x; i < 64*64; i += 256){
        int c = i & 63, r = i >> 6;
        Xs[r*68 + c] = X[(row0 + r)*64 + c];
    }
    for (int i = threadIdx.x; i < 64*64; i += 256){
        int c = i & 63, o = i >> 6;
        float a  = w[o*128 + c];
        Wp[c*68 + o] = a;
        Wq[c*68 + o] = w[o*128 + 64 + c] - a;
    }
    __syncthreads();
    float ap[4][4] = {{0.f}}, aq[4][4] = {{0.f}};
    for (int c0 = 0; c0 < 64; c0 += 4){
        float wp4[16], wq4[16];
        #pragma unroll
        for (int q = 0; q < 4; q++){
            *(float4*)&wp4[q*4] = *(const float4*)&Wp[(c0 + q)*68 + tx*4];
            *(float4*)&wq4[q*4] = *(const float4*)&Wq[(c0 + q)*68 + tx*4];
        }
        #pragma unroll
        for (int ii = 0; ii < 4; ii++){
            float4 x4 = *(const float4*)&Xs[(ty*4 + ii)*68 + c0];
            #pragma unroll
            for (int jj = 0; jj < 4; jj++){
                ap[ii][jj] += x4.x*wp4[jj] + x4.y*wp4[4+jj] + x4.z*wp4[8+jj] + x4.w*wp4[12+jj];
                aq[ii][jj] += x4.x*wq4[jj] + x4.y*wq4[4+jj] + x4.z*wq4[8+jj] + x4.w*wq4[12+jj];
            }
        }
    }
    #pragma unroll
    for (int ii = 0; ii < 4; ii++){
        int row = row0 + ty*4 + ii;
        store4(&P[row*64 + tx*4], ap[ii][0], ap[ii][1], ap[ii][2], ap[ii][3]);
        store4(&Q[row*64 + tx*4], aq[ii][0], aq[ii][1], aq[ii][2], aq[ii][3]);
    }
}

// ---------------- PASS A: stats of h = P[j]+Q[n]; optional fused max-over-k ----------------
template<bool DOMAX>
__global__ __launch_bounds__(256) void k_hstats(const float* __restrict__ P, const float* __restrict__ Q,
                                                const int* __restrict__ nbr, float* __restrict__ Xraw,
                                                double* __restrict__ dsum, double* __restrict__ dssq){
    __shared__ float sbuf[16*64];
    __shared__ float qbuf[16*64];
    int row0 = blockIdx.x * 80;
    int tx = threadIdx.x & 15, ty = threadIdx.x >> 4;
    int ng = (row0 + ty*5) / 20;
    int b  = ng >> 11;
    float4 q4 = *(const float4*)&Q[ng*64 + tx*4];
    float s[4] = {0.f,0.f,0.f,0.f}, s2[4] = {0.f,0.f,0.f,0.f};
    float m[4] = {-INFINITY,-INFINITY,-INFINITY,-INFINITY};
    #pragma unroll
    for (int ii = 0; ii < 5; ii++){
        int e = row0 + ty*5 + ii;
        int j = nbr[e];
        float4 p4 = *(const float4*)&P[((b << 11) + j)*64 + tx*4];
        float h0 = p4.x + q4.x, h1 = p4.y + q4.y, h2 = p4.z + q4.z, h3 = p4.w + q4.w;
        s[0] += h0; s[1] += h1; s[2] += h2; s[3] += h3;
        s2[0] += h0*h0; s2[1] += h1*h1; s2[2] += h2*h2; s2[3] += h3*h3;
        if (DOMAX){
            m[0] = fmaxf(m[0], h0); m[1] = fmaxf(m[1], h1);
            m[2] = fmaxf(m[2], h2); m[3] = fmaxf(m[3], h3);
        }
    }
    #pragma unroll
    for (int jj = 0; jj < 4; jj++){
        sbuf[ty*64 + tx*4 + jj] = s[jj];
        qbuf[ty*64 + tx*4 + jj] = s2[jj];
    }
    if (DOMAX){
        #pragma unroll
        for (int off = 32; off >= 16; off >>= 1){
            #pragma unroll
            for (int jj = 0; jj < 4; jj++) m[jj] = fmaxf(m[jj], __shfl_xor(m[jj], off));
        }
        int lane = threadIdx.x & 63;
        if (lane < 16){
            int pi = ty >> 2;
            store4(&Xraw[(row0/20 + pi)*64 + tx*4], m[0], m[1], m[2], m[3]);
        }
    }
    __syncthreads();
    if (threadIdx.x < 64){
        double t = 0.0;
        #pragma unroll
        for (int k = 0; k < 16; k++) t += (double)sbuf[k*64 + threadIdx.x];
        atomicAdd(&dsum[threadIdx.x], t);
    } else if (threadIdx.x < 128){
        int c = threadIdx.x - 64;
        double t = 0.0;
        #pragma unroll
        for (int k = 0; k < 16; k++) t += (double)qbuf[k*64 + c];
        atomicAdd(&dssq[c], t);
    }
}

// ---------------- PASS B: edge GEMM, fused stats + max-over-k ----------------
__global__ __launch_bounds__(256) void k_edgegemm(const float* __restrict__ P, const float* __restrict__ Q,
                                                  const int* __restrict__ nbr,
                                                  const float* __restrict__ sc, const float* __restrict__ sh,
                                                  const float* __restrict__ w,
                                                  float* __restrict__ Xraw,
                                                  double* __restrict__ dsum, double* __restrict__ dssq){
    __shared__ __align__(16) float Fs[80*68];
    __shared__ __align__(16) float Ws[64*68];
    __shared__ float sbuf[16*64];
    __shared__ float qbuf[16*64];
    int row0 = blockIdx.x * 80;
    for (int i = threadIdx.x; i < 80*64; i += 256){
        int c = i & 63, r = i >> 6;
        int e  = row0 + r;
        int ng = e / 20;
        int b  = ng >> 11;
        int j  = nbr[e];
        float h = P[((b << 11) + j)*64 + c] + Q[ng*64 + c];
        Fs[r*68 + c] = lrelu(h*sc[c] + sh[c]);
    }
    for (int i = threadIdx.x; i < 64*64; i += 256){
        int c = i & 63, o = i >> 6;
        Ws[c*68 + o] = w[o*64 + c];
    }
    __syncthreads();
    int tx = threadIdx.x & 15, ty = threadIdx.x >> 4;
    float acc[5][4] = {{0.f}};
    for (int c0 = 0; c0 < 64; c0 += 4){
        float bb4[16];
        #pragma unroll
        for (int q = 0; q < 4; q++)
            *(float4*)&bb4[q*4] = *(const float4*)&Ws[(c0 + q)*68 + tx*4];
        #pragma unroll
        for (int ii = 0; ii < 5; ii++){
            float4 a4 = *(const float4*)&Fs[(ty*5 + ii)*68 + c0];
            #pragma unroll
            for (int jj = 0; jj < 4; jj++)
                acc[ii][jj] += a4.x*bb4[jj] + a4.y*bb4[4+jj] + a4.z*bb4[8+jj] + a4.w*bb4[12+jj];
        }
    }
    float m[4];
    #pragma unroll
    for (int jj = 0; jj < 4; jj++){
        sbuf[ty*64 + tx*4 + jj] = acc[0][jj] + acc[1][jj] + acc[2][jj] + acc[3][jj] + acc[4][jj];
        qbuf[ty*64 + tx*4 + jj] = acc[0][jj]*acc[0][jj] + acc[1][jj]*acc[1][jj] + acc[2][jj]*acc[2][jj]
                                + acc[3][jj]*acc[3][jj] + acc[4][jj]*acc[4][jj];
        m[jj] = fmaxf(fmaxf(fmaxf(acc[0][jj], acc[1][jj]), fmaxf(acc[2][jj], acc[3][jj])), acc[4][jj]);
    }
    #pragma unroll
    for (int off = 32; off >= 16; off >>= 1){
        #pragma unroll
        for (int jj = 0; jj < 4; jj++) m[jj] = fmaxf(m[jj], __shfl_xor(m[jj], off));
    }
    int lane = threadIdx.x & 63;
    if (lane < 16){
        int pi = ty >> 2;
        store4(&Xraw[(row0/20 + pi)*64 + tx*4], m[0], m[1], m[2], m[3]);
    }
    __syncthreads();
    if (threadIdx.x < 64){
        double t = 0.0;
        #pragma unroll
        for (int k = 0; k < 16; k++) t += (double)sbuf[k*64 + threadIdx.x];
        atomicAdd(&dsum[threadIdx.x], t);
    } else if (threadIdx.x < 128){
        int c = threadIdx.x - 64;
        double t = 0.0;
        #pragma unroll
        for (int k = 0; k < 16; k++) t += (double)qbuf[k*64 + c];
        atomicAdd(&dssq[c], t);
    }
}

// ---------------- BN finalize ----------------
__global__ void k_finalize(const double* __restrict__ dsum, const double* __restrict__ dssq,
                           const float* __restrict__ g, const float* __restrict__ b,
                           float* __restrict__ scale, float* __restrict__ shift,
                           int ch, double inv_cnt){
    int c = blockIdx.x*256 + threadIdx.x;
    if (c >= ch) return;
    double m = dsum[c] * inv_cnt;
    double v = dssq[c] * inv_cnt - m*m;
    if (v < 0.0) v = 0.0;
    float rs = (float)(1.0 / sqrt(v + 1e-5));
    float sc = g[c] * rs;
    scale[c] = sc;
    shift[c] = b[c] - (float)m*sc;
}

// ---------------- in-place bn+lrelu on (16384 x 64) ----------------
__global__ void k_bnact(float* __restrict__ X, const float* __restrict__ sc, const float* __restrict__ sh){
    int t = blockIdx.x*256 + threadIdx.x;
    int c = t & 63;
    X[t] = lrelu(X[t]*sc[c] + sh[c]);
}

// ---------------- in-place bn8+lrelu on out1 (B,256,N) ----------------
__global__ void k_bnact8(float* __restrict__ O, const float* __restrict__ sc, const float* __restrict__ sh){
    int t = blockIdx.x*256 + threadIdx.x;
    int oc = (t >> 11) & 255;
    O[t] = lrelu(O[t]*sc[oc] + sh[oc]);
}

// ---------------- per-row squared norm ----------------
__global__ void k_sqnorm(const float* __restrict__ X, float* __restrict__ sqn){
    int row  = blockIdx.x*4 + (threadIdx.x >> 6);
    int lane = threadIdx.x & 63;
    float v = X[row*64 + lane];
    float s = v*v;
    #pragma unroll
    for (int off = 32; off >= 1; off >>= 1) s += __shfl_xor(s, off);
    if (lane == 0) sqn[row] = s;
}

// ---------------- Gram, up to 2 batches per dispatch: 128x128 tile, 8x8/thread ----------------
__global__ __launch_bounds__(256) void k_gram2(const float* __restrict__ X, float* G0, float* G1, int b0){
    __shared__ __align__(16) float As[32*132];
    __shared__ __align__(16) float Bs[32*132];
    int sub = blockIdx.x >> 8;
    int t   = blockIdx.x & 255;
    const float* Xb = X + (size_t)(b0 + sub)*NN*64;
    float* gram = sub ? G1 : G0;
    int tr = t >> 4, tc = t & 15;
    int tx = threadIdx.x & 15, ty = threadIdx.x >> 4;
    float acc[8][8];
    #pragma unroll
    for (int i = 0; i < 8; i++)
        #pragma unroll
        for (int j = 0; j < 8; j++) acc[i][j] = 0.f;
    for (int kc0 = 0; kc0 < 64; kc0 += 32){
        __syncthreads();
        for (int i = threadIdx.x; i < 128*32; i += 256){
            int k = i & 31, r = i >> 5;
            As[k*132 + r] = Xb[(tr*128 + r)*64 + kc0 + k];
            Bs[k*132 + r] = Xb[(tc*128 + r)*64 + kc0 + k];
        }
        __syncthreads();
        for (int k = 0; k < 32; k++){
            float4 a0 = *(const float4*)&As[k*132 + ty*8];
            float4 a1 = *(const float4*)&As[k*132 + ty*8 + 4];
            float4 b0v = *(const float4*)&Bs[k*132 + tx*8];
            float4 b1v = *(const float4*)&Bs[k*132 + tx*8 + 4];
            float av[8] = {a0.x,a0.y,a0.z,a0.w,a1.x,a1.y,a1.z,a1.w};
            float bv[8] = {b0v.x,b0v.y,b0v.z,b0v.w,b1v.x,b1v.y,b1v.z,b1v.w};
            #pragma unroll
            for (int i = 0; i < 8; i++)
                #pragma unroll
                for (int j = 0; j < 8; j++) acc[i][j] += av[i]*bv[j];
        }
    }
    #pragma unroll
    for (int i = 0; i < 8; i++){
        int row = tr*128 + ty*8 + i;
        *(float4*)&gram[row*NN + tc*128 + tx*8]     = make_float4(acc[i][0],acc[i][1],acc[i][2],acc[i][3]);
        *(float4*)&gram[row*NN + tc*128 + tx*8 + 4] = make_float4(acc[i][4],acc[i][5],acc[i][6],acc[i][7]);
    }
}

// ---------------- top-20 from gram rows, up to 2 batches per dispatch ----------------
__global__ __launch_bounds__(256) void k_sel2(const float* G0, const float* G1,
                                              const float* __restrict__ sqn, int* __restrict__ idx){
    __shared__ unsigned sval[4*64];
    __shared__ unsigned sidx[4*64];
    int sub = blockIdx.x >> 9;
    int rb  = blockIdx.x & 511;
    const float* gram = sub ? G1 : G0;
    const float* sq   = sqn + sub*NN;
    int lane = threadIdx.x & 63;
    int wid  = threadIdx.x >> 6;
    int n = rb*4 + wid;
    const float* grow = gram + (size_t)n*NN;
    float sn = sq[n];
    unsigned u[32];
    #pragma unroll
    for (int j = 0; j < 32; j++){
        int m = j*64 + lane;
        u[j] = f2sort(2.f*grow[m] - sn - sq[m]);
    }
    topk20(u, lane, sval + wid*64, sidx + wid*64, idx + (sub*NN + n)*KK);
}

// ---------------- C7 precompute ----------------
__global__ __launch_bounds__(256) void k_c7(const float* __restrict__ gmax, const float* __restrict__ w7,
                                            float* __restrict__ C7){
    __shared__ float red[4*8];
    int oc = blockIdx.x;
    int tid = threadIdx.x, lane = tid & 63, wid = tid >> 6;
    float a[8];
    #pragma unroll
    for (int b = 0; b < 8; b++) a[b] = 0.f;
    for (int k = tid; k < 1024; k += 256){
        float wv = w7[oc*1216 + k];
        #pragma unroll
        for (int b = 0; b < 8; b++) a[b] += gmax[b*1024 + k] * wv;
    }
    #pragma unroll
    for (int b = 0; b < 8; b++){
        #pragma unroll
        for (int off = 32; off >= 1; off >>= 1) a[b] += __shfl_xor(a[b], off);
        if (lane == 0) red[wid*8 + b] = a[b];
    }
    __syncthreads();
    if (tid < 8){
        float s = red[tid] + red[8 + tid] + red[16 + tid] + red[24 + tid];
        C7[tid*512 + oc] = s;
    }
}

// ---------------- unified head GEMM: 128x128 tile, 8x8/thread ----------------
template<int MODE, bool MAXN, int STMODE, typename TST, typename TH7>
__global__ __launch_bounds__(256) void k_head(
    const float* __restrict__ X1, const float* __restrict__ X2, const float* __restrict__ X3,
    const TH7*  __restrict__ H7, const float* __restrict__ C7,
    const float* __restrict__ sc_in, const float* __restrict__ sh_in,
    const float* __restrict__ w,
    TST* __restrict__ HST, float* __restrict__ out1t, float* __restrict__ part,
    double* __restrict__ dsum, double* __restrict__ dssq)
{
    constexpr int CIN  = (MODE == 4) ? 512 : 192;
    constexpr int WST  = (MODE == 2) ? 192 : (MODE == 3 ? 1216 : 512);
    constexpr int WOFF = (MODE == 3) ? 1024 : 0;
    constexpr int COUT = (MODE == 2) ? 1024 : (MODE == 3 ? 512 : 256);
    __shared__ __align__(16) float As[32*132];
    __shared__ __align__(16) float Bs[32*132];
    int tid = threadIdx.x;
    int rt = blockIdx.x & 127;
    int ct = blockIdx.x >> 7;
    int row0 = rt * 128;
    int col0 = ct * 128;
    int b = row0 >> 11;
    int tx = tid & 15, ty = tid >> 4;
    float acc[8][8];
    #pragma unroll
    for (int i = 0; i < 8; i++)
        #pragma unroll
        for (int j = 0; j < 8; j++) acc[i][j] = 0.f;
    for (int s = 0; s < CIN/32; s++){
        int cg0 = s*32;
        float scv = 0.f, shv = 0.f;
        if (MODE == 4){ scv = sc_in[cg0 + (tid & 31)]; shv = sh_in[cg0 + (tid & 31)]; }
        __syncthreads();
        for (int i = tid; i < 128*32; i += 256){
            int k = i & 31, r = i >> 5;
            float v;
            if (MODE == 4){
                v = lrelu((float)H7[(row0 + r)*512 + cg0 + k]*scv + shv);
            } else {
                const float* S = (cg0 < 64) ? X1 : (cg0 < 128 ? X2 : X3);
                int co = cg0 & 63;
                v = S[(row0 + r)*64 + co + k];
            }
            As[k*132 + r] = v;
        }
        for (int i = tid; i < 128*32; i += 256){
            int k = i & 31, n = i >> 5;
            Bs[k*132 + n] = w[(col0 + n)*WST + WOFF + cg0 + k];
        }
        __syncthreads();
        for (int k = 0; k < 32; k++){
            float4 a0 = *(const float4*)&As[k*132 + ty*8];
            float4 a1 = *(const float4*)&As[k*132 + ty*8 + 4];
            float4 b0 = *(const float4*)&Bs[k*132 + tx*8];
            float4 b1 = *(const float4*)&Bs[k*132 + tx*8 + 4];
            float av[8] = {a0.x,a0.y,a0.z,a0.w,a1.x,a1.y,a1.z,a1.w};
            float bv[8] = {b0.x,b0.y,b0.z,b0.w,b1.x,b1.y,b1.z,b1.w};
            #pragma unroll
            for (int i = 0; i < 8; i++)
                #pragma unroll
                for (int j = 0; j < 8; j++) acc[i][j] += av[i]*bv[j];
        }
    }
    if (MODE == 3){
        #pragma unroll
        for (int j = 0; j < 8; j++){
            float c7 = C7[b*512 + col0 + tx*8 + j];
            #pragma unroll
            for (int i = 0; i < 8; i++) acc[i][j] += c7;
        }
    }
    if (STMODE == 1){
        #pragma unroll
        for (int i = 0; i < 8; i++){
            int row = row0 + ty*8 + i;
            store4(&HST[row*COUT + col0 + tx*8],     acc[i][0], acc[i][1], acc[i][2], acc[i][3]);
            store4(&HST[row*COUT + col0 + tx*8 + 4], acc[i][4], acc[i][5], acc[i][6], acc[i][7]);
        }
    } else if (STMODE == 2){
        int n0 = (row0 & (NN-1)) + ty*8;
        #pragma unroll
        for (int j = 0; j < 8; j++){
            float* o = out1t + b*256*NN + (col0 + tx*8 + j)*NN + n0;
            *(float4*)o       = make_float4(acc[0][j], acc[1][j], acc[2][j], acc[3][j]);
            *(float4*)(o + 4) = make_float4(acc[4][j], acc[5][j], acc[6][j], acc[7][j]);
        }
    }
    __syncthreads();
    float* sbuf = As;
    float* qbuf = As + 2048;
    float* mbuf = Bs;
    #pragma unroll
    for (int j = 0; j < 8; j++){
        float sv = 0.f, qv = 0.f, mv = -INFINITY;
        #pragma unroll
        for (int i = 0; i < 8; i++){
            sv += acc[i][j];
            qv += acc[i][j]*acc[i][j];
            if (MAXN) mv = fmaxf(mv, acc[i][j]);
        }
        sbuf[ty*128 + tx*8 + j] = sv;
        qbuf[ty*128 + tx*8 + j] = qv;
        if (MAXN) mbuf[ty*128 + tx*8 + j] = mv;
    }
    __syncthreads();
    if (tid < 128){
        double t = 0.0;
        #pragma unroll
        for (int k = 0; k < 16; k++) t += (double)sbuf[k*128 + tid];
        atomicAdd(&dsum[col0 + tid], t);
        if (MAXN){
            float mm = -INFINITY;
            #pragma unroll
            for (int k = 0; k < 16; k++) mm = fmaxf(mm, mbuf[k*128 + tid]);
            part[rt*1024 + col0 + tid] = mm;
        }
    } else {
        int c = tid - 128;
        double t = 0.0;
        #pragma unroll
        for (int k = 0; k < 16; k++) t += (double)qbuf[k*128 + c];
        atomicAdd(&dssq[col0 + c], t);
    }
}

// ---------------- reduce partial maxes, apply bn6+lrelu ----------------
__global__ void k_gmax_fin(const float* __restrict__ part, const float* __restrict__ sc,
                           const float* __restrict__ sh, float* __restrict__ gmax){
    int t = blockIdx.x*256 + threadIdx.x;
    int b = t >> 10, c = t & 1023;
    float m = -INFINITY;
    #pragma unroll
    for (int k = 0; k < 16; k++) m = fmaxf(m, part[(b*16 + k)*1024 + c]);
    gmax[t] = lrelu(m*sc[c] + sh[c]);
}

// ---------------- tier C: BN8+lrelu + transpose from stored H8 bf16 ----------------
__global__ __launch_bounds__(256) void k_final_b(const bf16* __restrict__ H8,
                                                 const float* __restrict__ scale,
                                                 const float* __restrict__ shift,
                                                 float* __restrict__ out1){
    __shared__ float tile[64*65];
    int bi = blockIdx.x;
    int b  = bi / 128;
    int r  = bi % 128;
    int nt = r >> 2, ot = r & 3;
    for (int i = threadIdx.x; i < 64*64; i += 256){
        int o = i & 63, nl = i >> 6;
        float v = (float)H8[((b*NN) + nt*64 + nl)*256 + ot*64 + o];
        int oc = ot*64 + o;
        tile[o*65 + nl] = lrelu(v*scale[oc] + shift[oc]);
    }
    __syncthreads();
    for (int i = threadIdx.x; i < 64*64; i += 256){
        int nl = i & 63, o = i >> 6;
        out1[b*256*NN + (ot*64 + o)*NN + nt*64 + nl] = tile[o*65 + nl];
    }
}

// ---------------- host launcher ----------------
extern "C" void kernel_launch(void* const* d_in, const int* in_sizes, int n_in,
                              void* d_out, int out_size, void* d_ws, size_t ws_size,
                              hipStream_t stream){
    const float* x = (const float*)d_in[0];
    const float *w[8], *g[8], *bb[8];
    for (int i = 0; i < 8; i++){
        w[i]  = (const float*)d_in[1 + i*3];
        g[i]  = (const float*)d_in[2 + i*3];
        bb[i] = (const float*)d_in[3 + i*3];
    }
    float* ws  = (float*)d_ws;
    float* X1  = ws + OFF_X1;
    float* X2  = ws + OFF_X2;
    float* X3  = ws + OFF_X3;
    float* SQN = ws + OFF_SQN;
    float* GMAX= ws + OFF_GMAX;
    float* PART= ws + OFF_PART;
    float* C7  = ws + OFF_PART + 131072;
    double* DS = (double*)(ws + OFF_STATS);
    float*  FS = ws + OFF_STATS + 8448;
    int*   IDX = (int*)(ws + OFF_IDX);

    float* out0 = (float*)d_out;
    float* out1 = out0 + BB*NN*CC;
    float* P    = out1;
    float* Q    = out1 + 1048576;
    float* GRAM0= out1;
    float* GRAM1= ws + BASE_END;
    bool dualGram = ws_size >= (size_t)(BASE_END + 4194304)*4;

    const int chs[8]   = {64,64,64,64,64,1024,512,256};
    const int base[8]  = {0,128,256,384,512,640,2688,3712};
    double *SUMp[8], *SSQp[8];
    float  *SCp[8],  *SHp[8];
    for (int L = 0; L < 8; L++){
        SUMp[L] = DS + base[L];
        SSQp[L] = DS + base[L] + chs[L];
        SCp[L]  = FS + base[L];
        SHp[L]  = FS + base[L] + chs[L];
    }
    const double invE = 1.0 / (double)(BB*NN*KK);
    const double invP = 1.0 / (double)(BB*NN);

    hipMemsetAsync(DS, 0, 4224*sizeof(double), stream);
    k_echo<<<576,256,0,stream>>>(x, out0);

    // ---- stage 1 ----
    k_knn3<<<BB*NN/4,256,0,stream>>>(x, IDX);
    k_pq9<<<256,256,0,stream>>>(x, w[0], P, Q);
    k_hstats<false><<<4096,256,0,stream>>>(P, Q, IDX, nullptr, SUMp[0], SSQp[0]);
    k_finalize<<<1,256,0,stream>>>(SUMp[0],SSQp[0],g[0],bb[0],SCp[0],SHp[0],64,invE);
    k_edgegemm<<<4096,256,0,stream>>>(P, Q, IDX, SCp[0], SHp[0], w[1], X1, SUMp[1], SSQp[1]);
    k_finalize<<<1,256,0,stream>>>(SUMp[1],SSQp[1],g[1],bb[1],SCp[1],SHp[1],64,invE);
    k_bnact<<<4096,256,0,stream>>>(X1, SCp[1], SHp[1]);

    // ---- stage 2 & 3 knn + edge ----
    for (int stage = 0; stage < 2; stage++){
        float* Xs = (stage == 0) ? X1 : X2;
        k_sqnorm<<<4096,256,0,stream>>>(Xs, SQN);
        if (dualGram){
            for (int pr = 0; pr < 4; pr++){
                k_gram2<<<512,256,0,stream>>>(Xs, GRAM0, GRAM1, pr*2);
                k_sel2<<<1024,256,0,stream>>>(GRAM0, GRAM1, SQN + pr*2*NN, IDX + pr*2*NN*KK);
            }
        } else {
            for (int b = 0; b < BB; b++){
                k_gram2<<<256,256,0,stream>>>(Xs, GRAM0, GRAM0, b);
                k_sel2<<<512,256,0,stream>>>(GRAM0, GRAM0, SQN + b*NN, IDX + b*NN*KK);
            }
        }
        if (stage == 0){
            k_pq64<<<256,256,0,stream>>>(X1, w[2], P, Q);
            k_hstats<false><<<4096,256,0,stream>>>(P, Q, IDX, nullptr, SUMp[2], SSQp[2]);
            k_finalize<<<1,256,0,stream>>>(SUMp[2],SSQp[2],g[2],bb[2],SCp[2],SHp[2],64,invE);
            k_edgegemm<<<4096,256,0,stream>>>(P, Q, IDX, SCp[2], SHp[2], w[3], X2, SUMp[3], SSQp[3]);
            k_finalize<<<1,256,0,stream>>>(SUMp[3],SSQp[3],g[3],bb[3],SCp[3],SHp[3],64,invE);
            k_bnact<<<4096,256,0,stream>>>(X2, SCp[3], SHp[3]);
        } else {
            k_pq64<<<256,256,0,stream>>>(X2, w[4], P, Q);
            k_hstats<true><<<4096,256,0,stream>>>(P, Q, IDX, X3, SUMp[4], SSQp[4]);
            k_finalize<<<1,256,0,stream>>>(SUMp[4],SSQp[4],g[4],bb[4],SCp[4],SHp[4],64,invE);
            k_bnact<<<4096,256,0,stream>>>(X3, SCp[4], SHp[4]);
        }
    }

    // ---- layer 6 + global max ----
    k_head<2,true,0,float,float><<<1024,256,0,stream>>>(
        X1,X2,X3,(const float*)nullptr,nullptr,nullptr,nullptr,w[5],
        (float*)nullptr,nullptr,PART,SUMp[5],SSQp[5]);
    k_finalize<<<4,256,0,stream>>>(SUMp[5],SSQp[5],g[5],bb[5],SCp[5],SHp[5],1024,invP);
    k_gmax_fin<<<32,256,0,stream>>>(PART, SCp[5], SHp[5], GMAX);
    k_c7<<<512,256,0,stream>>>(GMAX, w[6], C7);

    // ---- layers 7/8, tiered by ws_size ----
    if (ws_size >= (size_t)12161536*4){
        float* H7f = ws + BASE_END;
        k_head<3,false,1,float,float><<<512,256,0,stream>>>(
            X1,X2,X3,(const float*)nullptr,C7,nullptr,nullptr,w[6],
            H7f,nullptr,nullptr,SUMp[6],SSQp[6]);
        k_finalize<<<2,256,0,stream>>>(SUMp[6],SSQp[6],g[6],bb[6],SCp[6],SHp[6],512,invP);
        k_head<4,false,2,float,float><<<256,256,0,stream>>>(
            nullptr,nullptr,nullptr,H7f,nullptr,SCp[6],SHp[6],w[7],
            (float*)nullptr,out1,nullptr,SUMp[7],SSQp[7]);
        k_finalize<<<1,256,0,stream>>>(SUMp[7],SSQp[7],g[7],bb[7],SCp[7],SHp[7],256,invP);
        k_bnact8<<<16384,256,0,stream>>>(out1, SCp[7], SHp[7]);
    } else if (ws_size >= (size_t)7967232*4){
        bf16* H7b = (bf16*)(ws + BASE_END);
        k_head<3,false,1,bf16,float><<<512,256,0,stream>>>(
            X1,X2,X3,(const float*)nullptr,C7,nullptr,nullptr,w[6],
            H7b,nullptr,nullptr,SUMp[6],SSQp[6]);
        k_finalize<<<2,256,0,stream>>>(SUMp[6],SSQp[6],g[6],bb[6],SCp[6],SHp[6],512,invP);
        k_head<4,false,2,float,bf16><<<256,256,0,stream>>>(
            nullptr,nullptr,nullptr,H7b,nullptr,SCp[6],SHp[6],w[7],
            (float*)nullptr,out1,nullptr,SUMp[7],SSQp[7]);
        k_finalize<<<1,256,0,stream>>>(SUMp[7],SSQp[7],g[7],bb[7],SCp[7],SHp[7],256,invP);
        k_bnact8<<<16384,256,0,stream>>>(out1, SCp[7], SHp[7]);
    } else {
        bf16* H7b = (bf16*)out1;
        bf16* H8b = (bf16*)(ws + OFF_X1);
        k_head<3,false,1,bf16,float><<<512,256,0,stream>>>(
            X1,X2,X3,(const float*)nullptr,C7,nullptr,nullptr,w[6],
            H7b,nullptr,nullptr,SUMp[6],SSQp[6]);
        k_finalize<<<2,256,0,stream>>>(SUMp[6],SSQp[6],g[6],bb[6],SCp[6],SHp[6],512,invP);
        k_head<4,false,1,bf16,bf16><<<256,256,0,stream>>>(
            nullptr,nullptr,nullptr,H7b,nullptr,SCp[6],SHp[6],w[7],
            H8b,nullptr,nullptr,SUMp[7],SSQp[7]);
        k_finalize<<<1,256,0,stream>>>(SUMp[7],SSQp[7],g[7],bb[7],SCp[7],SHp[7],256,invP);
        k_final_b<<<1024,256,0,stream>>>(H8b, SCp[7], SHp[7], out1);
    }
}